// Round 6
// baseline (311.275 us; speedup 1.0000x reference)
//
#include <hip/hip_runtime.h>
#include <hip/hip_bf16.h>

// SAGE reranker, round 6: LDS-free streamed MFMA GEMMs + frag-packed weights.
// R5 lesson: blockIdx.y mat-split re-read x 3x (FETCH 26->76MB, HBM-bound).
// Fix: mats fused SEQUENTIALLY per wave (A regs reused, x read once); B streamed
// from L2 in MFMA-frag order (prep pre-packs -> every B load = coalesced 1KB
// wave burst). Zero LDS, zero barriers in all GEMMs.

#define DIN 256
#define DH 128
#define NPB 512        // nodes per bucket (dst>>9)
#define NBMAX 128      // max buckets (N<=65536)
#define EPB 2048       // edges per partition block (391 blocks)
#define JL  (EPB/256)
#define CAP 14336      // LDS adj window capacity

typedef __attribute__((ext_vector_type(8))) short short8;
typedef __attribute__((ext_vector_type(4))) float float4v;

__device__ inline ushort f2b(float f){
  unsigned u = __float_as_uint(f);
  u = (u + 0x7fffu + ((u >> 16) & 1u)) >> 16;   // round-nearest-even
  return (ushort)u;
}
__device__ inline float blo(unsigned v){ return __uint_as_float(v << 16); }
__device__ inline float bhi(unsigned v){ return __uint_as_float(v & 0xffff0000u); }
__device__ inline short8 pack8(float4 f0, float4 f1){
  short8 v;
  v[0]=(short)f2b(f0.x); v[1]=(short)f2b(f0.y); v[2]=(short)f2b(f0.z); v[3]=(short)f2b(f0.w);
  v[4]=(short)f2b(f1.x); v[5]=(short)f2b(f1.y); v[6]=(short)f2b(f1.z); v[7]=(short)f2b(f1.w);
  return v;
}

// ---------------- CSR build (bucketed, coalesced writes only) ----------------
__global__ __launch_bounds__(256) void bucket_hist_kernel(
    const int* __restrict__ dst, int E, int NB, int* __restrict__ bucketCnt)
{
  __shared__ int hist[NBMAX];
  int t = threadIdx.x;
  for (int i=t;i<NB;i+=256) hist[i]=0;
  __syncthreads();
  int base = blockIdx.x * EPB;
  #pragma unroll
  for (int j=0;j<JL;j++){
    int e = base + j*256 + t;
    if (e < E) atomicAdd(&hist[dst[e] >> 9], 1);
  }
  __syncthreads();
  for (int i=t;i<NB;i+=256) atomicAdd(&bucketCnt[i], hist[i]);
}

__global__ void scan_buckets_kernel(const int* __restrict__ bucketCnt, int NB, int E,
                                    int* __restrict__ bucketBase, int* __restrict__ bucketCur,
                                    int* __restrict__ off, int N)
{
  __shared__ int s[NBMAX];
  int t = threadIdx.x;  // NBMAX threads
  s[t] = (t < NB)? bucketCnt[t] : 0;
  __syncthreads();
  for (int st=1; st<NBMAX; st<<=1){
    int v = (t>=st)? s[t-st] : 0;
    __syncthreads();
    s[t] += v;
    __syncthreads();
  }
  int excl = (t>0)? s[t-1] : 0;
  if (t < NB){ bucketBase[t] = excl; bucketCur[t] = excl; }
  if (t == NB) bucketBase[NB] = E;
  if (t == 0) off[N] = E;
}

__global__ __launch_bounds__(256) void partition_kernel(
    const int* __restrict__ src, const int* __restrict__ dst, int E, int NB,
    int* __restrict__ bucketCur, int* __restrict__ pairS, int* __restrict__ pairD)
{
  __shared__ int hist[NBMAX], lbase[NBMAX], gbase[NBMAX], lcur[NBMAX], sc[NBMAX];
  __shared__ int ls[EPB], ld[EPB];
  int t = threadIdx.x;
  int base = blockIdx.x * EPB;
  int cnt = E - base; if (cnt > EPB) cnt = EPB;
  for (int i=t;i<NB;i+=256) hist[i]=0;
  __syncthreads();
  int myS[JL], myD[JL];
  #pragma unroll
  for (int j=0;j<JL;j++){
    int e = base + j*256 + t;
    if (e < E){ myS[j]=src[e]; myD[j]=dst[e]; atomicAdd(&hist[myD[j]>>9],1); }
    else myD[j] = -1;
  }
  __syncthreads();
  if (t < NBMAX) sc[t] = (t < NB)? hist[t] : 0;
  __syncthreads();
  for (int st=1; st<NBMAX; st<<=1){
    int v = 0;
    if (t < NBMAX && t >= st) v = sc[t-st];
    __syncthreads();
    if (t < NBMAX) sc[t] += v;
    __syncthreads();
  }
  if (t < NB){
    int excl = (t>0)? sc[t-1] : 0;
    lbase[t] = excl; lcur[t] = excl;
    gbase[t] = atomicAdd(&bucketCur[t], hist[t]);
  }
  __syncthreads();
  #pragma unroll
  for (int j=0;j<JL;j++){
    if (myD[j] >= 0){
      int b = myD[j] >> 9;
      int p = atomicAdd(&lcur[b], 1);
      ls[p] = myS[j]; ld[p] = myD[j];
    }
  }
  __syncthreads();
  for (int i=t;i<cnt;i+=256){
    int d = ld[i];
    int b = d >> 9;
    int pos = gbase[b] + (i - lbase[b]);   // bucket-contiguous coalesced runs
    pairS[pos] = ls[i];
    pairD[pos] = d;
  }
}

__global__ __launch_bounds__(256) void bucket_csr_kernel(
    const int* __restrict__ bucketBase, const int* __restrict__ pairS,
    const int* __restrict__ pairD, int N, int* __restrict__ off, int* __restrict__ adj)
{
  __shared__ int cnt[NPB];
  __shared__ int offl[NPB+1];
  __shared__ int s1[256];
  __shared__ int win[CAP];
  int b = blockIdx.x;
  int t = threadIdx.x;
  int node0 = b * NPB;
  int base = bucketBase[b], end = bucketBase[b+1];
  int ce = end - base;
  for (int i=t;i<NPB;i+=256) cnt[i]=0;
  __syncthreads();
  for (int i=t;i<ce;i+=256) atomicAdd(&cnt[pairD[base+i]-node0], 1);
  __syncthreads();
  int a0 = cnt[2*t], a1 = cnt[2*t+1];
  s1[t] = a0 + a1;
  __syncthreads();
  for (int st=1; st<256; st<<=1){
    int v = (t>=st)? s1[t-st] : 0;
    __syncthreads();
    s1[t] += v;
    __syncthreads();
  }
  int excl = (t>0)? s1[t-1] : 0;
  offl[2*t] = excl; offl[2*t+1] = excl + a0;
  if (t == 255) offl[NPB] = s1[255];
  __syncthreads();
  for (int i=t;i<NPB;i+=256){
    int node = node0 + i;
    if (node <= N) off[node] = base + offl[i];
  }
  __syncthreads();
  // offl reused as cursor
  if (ce <= CAP){
    for (int i=t;i<ce;i+=256){
      int d = pairD[base+i];
      int p = atomicAdd(&offl[d-node0], 1);
      win[p] = pairS[base+i];          // LDS scatter: random ~2-way, free
    }
    __syncthreads();
    for (int i=t;i<ce;i+=256) adj[base+i] = win[i];   // coalesced dump
  } else {
    for (int i=t;i<ce;i+=256){
      int d = pairD[base+i];
      int p = atomicAdd(&offl[d-node0], 1);
      adj[base+p] = pairS[base+i];     // overflow fallback (never for this input)
    }
  }
}

// ------------- weight prep: frag-packed bf16 -------------
// granule i = (ks*(cols/16) + nt)*64 + ln holds B-frag 16B for (ks,nt,lane=ln):
// col = nt*16 + (ln&15), k = ks*32 + (ln>>4)*8 + j. GEMM B-load = 1KB coalesced burst.
__global__ __launch_bounds__(256) void prep_wf_kernel(
    const float* __restrict__ Wp, const float* __restrict__ Wl0, const float* __restrict__ Wr0,
    const float* __restrict__ Wl1, const float* __restrict__ Wr1, const float* __restrict__ W1,
    ushort* __restrict__ Wpf, ushort* __restrict__ Wl0f, ushort* __restrict__ Wr0f,
    ushort* __restrict__ Wl1f, ushort* __restrict__ Wr1f, ushort* __restrict__ W1f)
{
  const float* src; ushort* dst; int K, cols;
  switch (blockIdx.y){
    case 0: src=Wp;  dst=Wpf;  K=256; cols=128; break;
    case 1: src=Wl0; dst=Wl0f; K=256; cols=128; break;
    case 2: src=Wr0; dst=Wr0f; K=256; cols=128; break;
    case 3: src=Wl1; dst=Wl1f; K=128; cols=128; break;
    case 4: src=Wr1; dst=Wr1f; K=128; cols=128; break;
    default:src=W1;  dst=W1f;  K=128; cols=64;  break;
  }
  int ntq = cols >> 4;
  int G = (K >> 5) * ntq * 64;
  int i = blockIdx.x*256 + threadIdx.x;
  if (i >= G) return;
  int ln = i & 63;
  int g  = i >> 6;
  int nt = g % ntq;
  int ks = g / ntq;
  int col = nt*16 + (ln & 15);
  int k0  = ks*32 + (ln >> 4)*8;
  short8 v;
  #pragma unroll
  for (int j=0;j<8;j++) v[j] = (short)f2b(src[(size_t)(k0+j)*cols + col]);
  *(short8*)(dst + (size_t)i*8) = v;
}

// ------------- streamed GEMM: Ym = A @ Wm (+bias on mat0), NM mats sequential -------------
// One 16-row stripe per wave. A-frags global->reg once (reused across mats);
// B-frags streamed from L2 (frag-packed, 1KB coalesced). No LDS, no barriers.
template<int K, int NM, bool AFP32>
__global__ __launch_bounds__(256) void gemm_stream(
    const void* __restrict__ Av, int nrows,
    const ushort* __restrict__ Wf0, const ushort* __restrict__ Wf1, const ushort* __restrict__ Wf2,
    const float* __restrict__ bias0,
    ushort* __restrict__ Y0, ushort* __restrict__ Y1, ushort* __restrict__ Y2)
{
  constexpr int KS = K / 32;
  int t = threadIdx.x, w = t >> 6, lane = t & 63;
  int lq = lane & 15, quad = lane >> 4;
  int row0 = (blockIdx.x*4 + w) * 16;
  if (row0 >= nrows) return;
  int arow = row0 + lq; if (arow >= nrows) arow = nrows - 1;

  short8 av[KS];
  #pragma unroll
  for (int ks=0; ks<KS; ks++){
    if (AFP32){
      const float* p = (const float*)Av + (size_t)arow*K + ks*32 + quad*8;
      av[ks] = pack8(*(const float4*)p, *(const float4*)(p+4));
    } else {
      av[ks] = *(const short8*)((const ushort*)Av + (size_t)arow*K + ks*32 + quad*8);
    }
  }

  #pragma unroll
  for (int m=0; m<NM; m++){
    const ushort* Wf = (m==0)? Wf0 : (m==1)? Wf1 : Wf2;
    ushort* Ym       = (m==0)? Y0  : (m==1)? Y1  : Y2;
    float4v acc[8];
    #pragma unroll
    for (int nt=0;nt<8;nt++)
      #pragma unroll
      for (int r=0;r<4;r++) acc[nt][r] = 0.f;
    #pragma unroll
    for (int ks=0; ks<KS; ks++){
      #pragma unroll
      for (int nt=0; nt<8; nt++){
        short8 bf = *(const short8*)(Wf + (size_t)(((ks*8 + nt)<<6) + lane)*8);
        acc[nt] = __builtin_amdgcn_mfma_f32_16x16x32_bf16(av[ks], bf, acc[nt], 0,0,0);
      }
    }
    #pragma unroll
    for (int nt=0; nt<8; nt++){
      float b = (m==0 && bias0)? bias0[nt*16 + lq] : 0.f;
      #pragma unroll
      for (int r=0; r<4; r++){
        int row = row0 + quad*4 + r;
        if (row < nrows)
          Ym[(size_t)row*128 + nt*16 + lq] = f2b(acc[nt][r] + b);
      }
    }
  }
}

// ------------- streamed head GEMM fused with W2 dot + alpha mix -------------
// s1 = relu(A@W1 + b1) [16-stripe][64]; out = a*rer + (1-a)*(s1.W2 + b2)
__global__ __launch_bounds__(256) void gemm_head_stream(
    const ushort* __restrict__ A, int nrows,
    const ushort* __restrict__ W1f, const float* __restrict__ b1,
    const float* __restrict__ W2, const float* __restrict__ b2,
    const float* __restrict__ alogit, const float* __restrict__ rer,
    float* __restrict__ out)
{
  int t = threadIdx.x, w = t >> 6, lane = t & 63;
  int lq = lane & 15, quad = lane >> 4;
  int row0 = (blockIdx.x*4 + w) * 16;
  if (row0 >= nrows) return;
  int arow = row0 + lq; if (arow >= nrows) arow = nrows - 1;

  short8 av[4];
  #pragma unroll
  for (int ks=0; ks<4; ks++)
    av[ks] = *(const short8*)(A + (size_t)arow*128 + ks*32 + quad*8);

  float4v acc[4];
  #pragma unroll
  for (int nt=0;nt<4;nt++)
    #pragma unroll
    for (int r=0;r<4;r++) acc[nt][r] = 0.f;
  #pragma unroll
  for (int ks=0; ks<4; ks++){
    #pragma unroll
    for (int nt=0; nt<4; nt++){
      short8 bf = *(const short8*)(W1f + (size_t)(((ks*4 + nt)<<6) + lane)*8);
      acc[nt] = __builtin_amdgcn_mfma_f32_16x16x32_bf16(av[ks], bf, acc[nt], 0,0,0);
    }
  }

  float al = alogit[0];
  float a  = 1.f / (1.f + __expf(-al));
  float pw[4] = {0.f,0.f,0.f,0.f};
  #pragma unroll
  for (int nt=0; nt<4; nt++){
    int c = nt*16 + lq;
    float w2 = W2[c];
    float bb = b1[c];
    #pragma unroll
    for (int r=0; r<4; r++)
      pw[r] += fmaxf(acc[nt][r] + bb, 0.f) * w2;
  }
  #pragma unroll
  for (int mask=1; mask<16; mask<<=1){
    #pragma unroll
    for (int r=0; r<4; r++)
      pw[r] += __shfl_xor(pw[r], mask);
  }
  if (lq == 0){
    #pragma unroll
    for (int r=0; r<4; r++){
      int row = row0 + quad*4 + r;
      if (row < nrows)
        out[row] = a * rer[row] + (1.f - a) * (pw[r] + b2[0]);
    }
  }
}

// ---------------- combine: out = bf16(relu(mean_agg + bias + root) + res) ----------------
__global__ __launch_bounds__(256) void combine_b_kernel(
    const ushort* __restrict__ aggsrc, const ushort* __restrict__ rootsrc,
    const ushort* __restrict__ ressrc, const float* __restrict__ bias,
    const int* __restrict__ off, const int* __restrict__ adj,
    ushort* __restrict__ out, int n)
{
  int t = threadIdx.x;
  int d = t & 63;
  int node = blockIdx.x*4 + (t >> 6);
  if (node >= n) return;
  int s = off[node], e = off[node+1];
  const unsigned* aggu = (const unsigned*)aggsrc;
  float a0 = 0.f, a1 = 0.f;
  int p = s;
  for (; p+8 <= e; p += 8){
    unsigned v0 = aggu[(size_t)adj[p  ]*64 + d];
    unsigned v1 = aggu[(size_t)adj[p+1]*64 + d];
    unsigned v2 = aggu[(size_t)adj[p+2]*64 + d];
    unsigned v3 = aggu[(size_t)adj[p+3]*64 + d];
    unsigned v4 = aggu[(size_t)adj[p+4]*64 + d];
    unsigned v5 = aggu[(size_t)adj[p+5]*64 + d];
    unsigned v6 = aggu[(size_t)adj[p+6]*64 + d];
    unsigned v7 = aggu[(size_t)adj[p+7]*64 + d];
    a0 += ((blo(v0)+blo(v1)) + (blo(v2)+blo(v3))) + ((blo(v4)+blo(v5)) + (blo(v6)+blo(v7)));
    a1 += ((bhi(v0)+bhi(v1)) + (bhi(v2)+bhi(v3))) + ((bhi(v4)+bhi(v5)) + (bhi(v6)+bhi(v7)));
  }
  for (; p+4 <= e; p += 4){
    unsigned v0 = aggu[(size_t)adj[p  ]*64 + d];
    unsigned v1 = aggu[(size_t)adj[p+1]*64 + d];
    unsigned v2 = aggu[(size_t)adj[p+2]*64 + d];
    unsigned v3 = aggu[(size_t)adj[p+3]*64 + d];
    a0 += (blo(v0)+blo(v1)) + (blo(v2)+blo(v3));
    a1 += (bhi(v0)+bhi(v1)) + (bhi(v2)+bhi(v3));
  }
  for (; p < e; p++){
    unsigned v = aggu[(size_t)adj[p]*64 + d];
    a0 += blo(v); a1 += bhi(v);
  }
  int cnt = e - s;
  float inv = 1.f / (float)((cnt > 1)? cnt : 1);
  unsigned rt = ((const unsigned*)rootsrc)[(size_t)node*64 + d];
  unsigned rs = ((const unsigned*)ressrc)[(size_t)node*64 + d];
  float o0 = fmaxf(a0*inv + bias[2*d]   + blo(rt), 0.f) + blo(rs);
  float o1 = fmaxf(a1*inv + bias[2*d+1] + bhi(rt), 0.f) + bhi(rs);
  ((unsigned*)out)[(size_t)node*64 + d] = (unsigned)f2b(o0) | ((unsigned)f2b(o1) << 16);
}

extern "C" void kernel_launch(void* const* d_in, const int* in_sizes, int n_in,
                              void* d_out, int out_size, void* d_ws, size_t ws_size,
                              hipStream_t stream)
{
  (void)n_in; (void)out_size; (void)ws_size;
  const float* x    = (const float*)d_in[0];
  const int*   ei   = (const int*)d_in[1];
  const float* rer  = (const float*)d_in[2];
  const float* Wp   = (const float*)d_in[3];
  const float* bp   = (const float*)d_in[4];
  const float* Wl0  = (const float*)d_in[5];
  const float* bl0  = (const float*)d_in[6];
  const float* Wr0  = (const float*)d_in[7];
  const float* Wl1  = (const float*)d_in[8];
  const float* bl1  = (const float*)d_in[9];
  const float* Wr1  = (const float*)d_in[10];
  const float* W1   = (const float*)d_in[11];
  const float* b1   = (const float*)d_in[12];
  const float* W2   = (const float*)d_in[13];
  const float* b2   = (const float*)d_in[14];
  const float* alogit = (const float*)d_in[15];

  const int N = in_sizes[2];      // 50000
  const int E = in_sizes[1] / 2;  // 800000
  const int* src = ei;
  const int* dst = ei + E;
  const int NB = (N + NPB - 1) / NPB;   // 98

  // workspace layout
  ushort* U = (ushort*)d_ws;
  ushort* xp  = U;                         // [N][128] residual; reused as h2
  ushort* xl0 = xp  + (size_t)N*DH;        // reused as hl1
  ushort* xr0 = xl0 + (size_t)N*DH;        // reused as hr1
  ushort* h   = xr0 + (size_t)N*DH;
  ushort* Wpf  = h    + (size_t)N*DH;      // frag-packed weights
  ushort* Wl0f = Wpf  + 256*128;
  ushort* Wr0f = Wl0f + 256*128;
  ushort* Wl1f = Wr0f + 256*128;
  ushort* Wr1f = Wl1f + 128*128;
  ushort* W1f  = Wr1f + 128*128;
  int* I = (int*)(W1f + 128*64);
  int* bucketCnt  = I;                   // NBMAX
  int* bucketBase = bucketCnt + NBMAX;   // NBMAX+1
  int* bucketCur  = bucketBase + NBMAX + 1;
  int* off   = bucketCur + NBMAX;        // N+1
  int* pairS = off + (N+1);              // E
  int* pairD = pairS + E;                // E
  int* adj   = pairD + E;                // E

  // weight prep (independent)
  prep_wf_kernel<<<dim3(16,6), 256, 0, stream>>>(Wp,Wl0,Wr0,Wl1,Wr1,W1,
                                                 Wpf,Wl0f,Wr0f,Wl1f,Wr1f,W1f);

  // CSR build, coalesced
  hipMemsetAsync(bucketCnt, 0, NBMAX*sizeof(int), stream);
  int gP = (E + EPB - 1) / EPB;   // 391
  bucket_hist_kernel<<<gP, 256, 0, stream>>>(dst, E, NB, bucketCnt);
  scan_buckets_kernel<<<1, NBMAX, 0, stream>>>(bucketCnt, NB, E, bucketBase, bucketCur, off, N);
  partition_kernel<<<gP, 256, 0, stream>>>(src, dst, E, NB, bucketCur, pairS, pairD);
  bucket_csr_kernel<<<NB, 256, 0, stream>>>(bucketBase, pairS, pairD, N, off, adj);

  int gx = (N/16 + 3) / 4;   // 782 blocks (3125 stripes, 1/wave)

  // GEMM0 (x read once, mats sequential): xp = x@Wp+bp ; xl0 = x@Wl0 ; xr0 = x@Wr0
  gemm_stream<256,3,true><<<gx, 256, 0, stream>>>(x, N, Wpf, Wl0f, Wr0f, bp, xp, xl0, xr0);
  // h = relu(mean(xl0[nbrs]) + bl0 + xr0) + xp
  combine_b_kernel<<<(N+3)/4, 256, 0, stream>>>(xl0, xr0, xp, bl0, off, adj, h, N);

  // GEMM1: hl1 = h@Wl1 ; hr1 = h@Wr1
  gemm_stream<128,2,false><<<gx, 256, 0, stream>>>(h, N, Wl1f, Wr1f, nullptr, nullptr, xl0, xr0, nullptr);
  // h2 = relu(mean(hl1[nbrs]) + bl1 + hr1) + h   (h2 -> xp)
  combine_b_kernel<<<(N+3)/4, 256, 0, stream>>>(xl0, xr0, h, bl1, off, adj, xp, N);

  // head fused: out = a*rer + (1-a)*(relu(xp@W1+b1) . W2 + b2)
  gemm_head_stream<<<gx, 256, 0, stream>>>(xp, N, W1f, b1, W2, b2, alogit, rer, (float*)d_out);
}

// Round 7
// 299.026 us; speedup vs baseline: 1.0410x; 1.0410x over previous
//
#include <hip/hip_runtime.h>
#include <hip/hip_bf16.h>

// SAGE reranker, round 7: async glds pipeline + kernel fusion.
//  - GEMM0: A pre-packed frag-major (convert role), B frag-major (prep role);
//    staging via __builtin_amdgcn_global_load_lds dwordx4, double-buffered:
//    loads for step k+1 issued right after barrier k -> fly during MFMA(k).
//    One barrier/step, zero ds_writes, zero conflicts (frag layout, R5-proven).
//  - CSR scan-free: fixed-stride (SLOTS) buckets + deg[] array; hist/scan deleted.
//  - Launch fusion: L1=[partition|convert|prep], L2=[gemm0|bucket_csr].
//  - GEMM1/head: weights-resident via glds, A global->reg, ONE barrier total.

#define DIN 256
#define DH 128
#define NPB 512
#define NBMAX 128
#define EPB 2048
#define JL (EPB/256)
#define CAP 14336
#define SLOTS 16384

typedef __attribute__((ext_vector_type(8))) short short8;
typedef __attribute__((ext_vector_type(4))) float float4v;

__device__ inline ushort f2b(float f){
  unsigned u = __float_as_uint(f);
  u = (u + 0x7fffu + ((u >> 16) & 1u)) >> 16;   // round-nearest-even
  return (ushort)u;
}
__device__ inline float blo(unsigned v){ return __uint_as_float(v << 16); }
__device__ inline float bhi(unsigned v){ return __uint_as_float(v & 0xffff0000u); }
__device__ inline short8 pack8(float4 f0, float4 f1){
  short8 v;
  v[0]=(short)f2b(f0.x); v[1]=(short)f2b(f0.y); v[2]=(short)f2b(f0.z); v[3]=(short)f2b(f0.w);
  v[4]=(short)f2b(f1.x); v[5]=(short)f2b(f1.y); v[6]=(short)f2b(f1.z); v[7]=(short)f2b(f1.w);
  return v;
}

// async global->LDS, 16B per lane. LDS dest = wave-uniform base + lane*16.
__device__ inline void glds16(const ushort* g, ushort* l){
  __builtin_amdgcn_global_load_lds((const __attribute__((address_space(1))) void*)g,
                                   (__attribute__((address_space(3))) void*)l, 16, 0, 0);
}

// ================= L1: fused front: [partition | convert-x | weight prep] =================
__global__ __launch_bounds__(256) void fused_front(
    const float* __restrict__ x, int N, ushort* __restrict__ xb,
    const float* __restrict__ Wp, const float* __restrict__ Wl0, const float* __restrict__ Wr0,
    const float* __restrict__ Wl1, const float* __restrict__ Wr1, const float* __restrict__ W1,
    ushort* __restrict__ Wpf, ushort* __restrict__ Wl0f, ushort* __restrict__ Wr0f,
    ushort* __restrict__ Wl1f, ushort* __restrict__ Wr1f, ushort* __restrict__ W1f,
    const int* __restrict__ src, const int* __restrict__ dst, int E, int NB,
    int* __restrict__ bucketCnt, int* __restrict__ pairS, int* __restrict__ pairD,
    int nPart, int nConv)
{
  __shared__ int hist[NBMAX], lbase[NBMAX], gbase[NBMAX], lcur[NBMAX], sc[NBMAX];
  __shared__ int ls[EPB], ld[EPB];
  int bid = blockIdx.x;
  int t = threadIdx.x;

  if (bid < nPart){
    // ---- partition role: LDS counting-sort, one global atomic per bucket ----
    int base = bid * EPB;
    int cntE = E - base; if (cntE > EPB) cntE = EPB;
    for (int i=t;i<NB;i+=256) hist[i]=0;
    __syncthreads();
    int myS[JL], myD[JL];
    #pragma unroll
    for (int j=0;j<JL;j++){
      int e = base + j*256 + t;
      if (e < E){ myS[j]=src[e]; myD[j]=dst[e]; atomicAdd(&hist[myD[j]>>9],1); }
      else myD[j] = -1;
    }
    __syncthreads();
    if (t < NBMAX) sc[t] = (t < NB)? hist[t] : 0;
    __syncthreads();
    for (int st=1; st<NBMAX; st<<=1){
      int v = 0;
      if (t < NBMAX && t >= st) v = sc[t-st];
      __syncthreads();
      if (t < NBMAX) sc[t] += v;
      __syncthreads();
    }
    if (t < NB){
      int excl = (t>0)? sc[t-1] : 0;
      lbase[t] = excl; lcur[t] = excl;
      gbase[t] = atomicAdd(&bucketCnt[t], hist[t]);
    }
    __syncthreads();
    #pragma unroll
    for (int j=0;j<JL;j++){
      if (myD[j] >= 0){
        int b = myD[j] >> 9;
        int p = atomicAdd(&lcur[b], 1);
        ls[p] = myS[j]; ld[p] = myD[j];
      }
    }
    __syncthreads();
    for (int i=t;i<cntE;i+=256){
      int d = ld[i];
      int b = d >> 9;
      int p = gbase[b] + (i - lbase[b]);
      if (p < SLOTS){
        pairS[(size_t)b*SLOTS + p] = ls[i];
        pairD[(size_t)b*SLOTS + p] = d;
      }
    }
  } else if (bid < nPart + nConv){
    // ---- convert role: x fp32 -> xb bf16 in A-frag-major layout ----
    // granule gi: L=gi&63, ks=(gi>>6)&7, wm=(gi>>9)&7, tile=gi>>12
    // holds A[row=tile*128+wm*16+(L&15)][k=ks*32+(L>>4)*8 .. +8]
    int gi = (bid - nPart)*256 + t;
    int L = gi & 63, ks = (gi>>6)&7, wm = (gi>>9)&7, tile = gi>>12;
    int row = tile*128 + wm*16 + (L&15);
    int k = ks*32 + (L>>4)*8;
    short8 v;
    if (row < N){
      const float* p = x + (size_t)row*DIN + k;
      v = pack8(*(const float4*)p, *(const float4*)(p+4));
    } else {
      #pragma unroll
      for (int j=0;j<8;j++) v[j]=0;
    }
    *(short8*)(xb + (size_t)gi*8) = v;
  } else {
    // ---- prep role: weights -> B-frag-major bf16 ----
    int gi = (bid - nPart - nConv)*256 + t;   // 0..17407
    const float* sw; ushort* dw; int cols, b0;
    if      (gi <  4096){ sw=Wp;  dw=Wpf;  cols=128; b0=0; }
    else if (gi <  8192){ sw=Wl0; dw=Wl0f; cols=128; b0=4096; }
    else if (gi < 12288){ sw=Wr0; dw=Wr0f; cols=128; b0=8192; }
    else if (gi < 14336){ sw=Wl1; dw=Wl1f; cols=128; b0=12288; }
    else if (gi < 16384){ sw=Wr1; dw=Wr1f; cols=128; b0=14336; }
    else                { sw=W1;  dw=W1f;  cols=64;  b0=16384; }
    int i = gi - b0;
    int ln = i & 63, g = i >> 6;
    int ntq = cols >> 4;
    int nt = g % ntq, ks = g / ntq;
    int col = nt*16 + (ln & 15);
    int k0 = ks*32 + (ln >> 4)*8;
    short8 v;
    #pragma unroll
    for (int j=0;j<8;j++) v[j] = (short)f2b(sw[(size_t)(k0+j)*cols + col]);
    *(short8*)(dw + (size_t)i*8) = v;
  }
}

// ================= L2: fused [GEMM0 (async dbuf) | bucket_csr] =================
__global__ __launch_bounds__(256) void fused_gemm0_csr(
    const ushort* __restrict__ xb, int N, int ntile,
    const ushort* __restrict__ Wpf, const ushort* __restrict__ Wl0f, const ushort* __restrict__ Wr0f,
    const float* __restrict__ bp,
    ushort* __restrict__ xp, ushort* __restrict__ xl0, ushort* __restrict__ xr0,
    const int* __restrict__ bucketCnt, const int* __restrict__ pairS, const int* __restrict__ pairD,
    int* __restrict__ off, int* __restrict__ deg, int* __restrict__ adj, int NB)
{
  __shared__ __align__(16) ushort smem[32768];   // 64 KB union
  int bid = blockIdx.x, t = threadIdx.x;

  if (bid < ntile){
    // ---- GEMM0 role: xp=x@Wp+bp ; xl0=x@Wl0 ; xr0=x@Wr0 ----
    ushort* A0 = smem;            // 4096 ushorts (8 KB)
    ushort* A1 = smem + 4096;
    ushort* B0 = smem + 8192;     // 12288 ushorts (24 KB)
    ushort* B1 = smem + 20480;
    int w = t>>6, lane = t&63, lq = lane&15, quad = lane>>4;
    int tile = bid;

    auto stage = [&](int ks, ushort* Ab, ushort* Bb){
      #pragma unroll
      for (int mt=0; mt<2; mt++){
        int wm = w*2+mt;
        glds16(xb + (((size_t)tile*8 + wm)*8 + ks)*512 + lane*8, Ab + wm*512);
      }
      #pragma unroll
      for (int j=0; j<6; j++){
        int r = w + j*4;
        int m = r>>3, nt = r&7;
        const ushort* Wm = (m==0)? Wpf : (m==1)? Wl0f : Wr0f;
        glds16(Wm + (size_t)(ks*8+nt)*512 + lane*8, Bb + r*512);
      }
    };

    float4v acc[3][2][8];
    #pragma unroll
    for (int m=0;m<3;m++)
      #pragma unroll
      for (int i=0;i<2;i++)
        #pragma unroll
        for (int j=0;j<8;j++)
          #pragma unroll
          for (int r=0;r<4;r++) acc[m][i][j][r] = 0.f;

    stage(0, A0, B0);
    #pragma unroll
    for (int ks=0; ks<8; ks++){
      __syncthreads();                               // drains glds for step ks
      if (ks < 7) stage(ks+1, (ks&1)?A0:A1, (ks&1)?B0:B1);  // fly during MFMA(ks)
      const ushort* Ab = (ks&1)? A1 : A0;
      const ushort* Bb = (ks&1)? B1 : B0;
      short8 af0 = *(const short8*)(Ab + ((w*2+0)*64 + lane)*8);
      short8 af1 = *(const short8*)(Ab + ((w*2+1)*64 + lane)*8);
      #pragma unroll
      for (int m=0;m<3;m++){
        #pragma unroll
        for (int nt=0;nt<8;nt++){
          short8 bf = *(const short8*)(Bb + ((m*8+nt)*64 + lane)*8);
          acc[m][0][nt] = __builtin_amdgcn_mfma_f32_16x16x32_bf16(af0, bf, acc[m][0][nt], 0,0,0);
          acc[m][1][nt] = __builtin_amdgcn_mfma_f32_16x16x32_bf16(af1, bf, acc[m][1][nt], 0,0,0);
        }
      }
    }
    #pragma unroll
    for (int m=0;m<3;m++){
      ushort* Ym = (m==0)? xp : (m==1)? xl0 : xr0;
      #pragma unroll
      for (int mt=0;mt<2;mt++){
        #pragma unroll
        for (int r=0;r<4;r++){
          int row = tile*128 + w*32 + mt*16 + quad*4 + r;
          if (row < N){
            #pragma unroll
            for (int nt=0;nt<8;nt++){
              float v = acc[m][mt][nt][r];
              if (m==0) v += bp[nt*16 + lq];
              Ym[(size_t)row*128 + nt*16 + lq] = f2b(v);
            }
          }
        }
      }
    }
  } else {
    // ---- bucket_csr role ----
    int b = bid - ntile;
    int* cnt  = (int*)smem;            // NPB
    int* offl = cnt + NPB;             // NPB+1
    int* s1   = offl + NPB + 1;        // 256
    int* win  = s1 + 256;              // CAP
    int node0 = b * NPB;
    int base  = b * SLOTS;
    int ce = bucketCnt[b]; if (ce > SLOTS) ce = SLOTS;
    for (int i=t;i<NPB;i+=256) cnt[i]=0;
    __syncthreads();
    for (int i=t;i<ce;i+=256) atomicAdd(&cnt[pairD[(size_t)base+i]-node0], 1);
    __syncthreads();
    int a0 = cnt[2*t], a1 = cnt[2*t+1];
    s1[t] = a0 + a1;
    __syncthreads();
    for (int st=1; st<256; st<<=1){
      int v = (t>=st)? s1[t-st] : 0;
      __syncthreads();
      s1[t] += v;
      __syncthreads();
    }
    int excl = (t>0)? s1[t-1] : 0;
    offl[2*t] = excl; offl[2*t+1] = excl + a0;
    __syncthreads();
    for (int i=t;i<NPB;i+=256){
      int node = node0 + i;
      if (node < N){ off[node] = base + offl[i]; deg[node] = cnt[i]; }
    }
    __syncthreads();
    // offl reused as cursor
    if (ce <= CAP){
      for (int i=t;i<ce;i+=256){
        int d = pairD[(size_t)base+i];
        int p = atomicAdd(&offl[d-node0], 1);
        win[p] = pairS[(size_t)base+i];
      }
      __syncthreads();
      for (int i=t;i<ce;i+=256) adj[(size_t)base+i] = win[i];
    } else {
      for (int i=t;i<ce;i+=256){
        int d = pairD[(size_t)base+i];
        int p = atomicAdd(&offl[d-node0], 1);
        adj[(size_t)base+p] = pairS[(size_t)base+i];
      }
    }
  }
}

// ================= GEMM1: weights-resident, one barrier =================
__global__ __launch_bounds__(256) void gemm1_wres(
    const ushort* __restrict__ h, int N,
    const ushort* __restrict__ Wl1f, const ushort* __restrict__ Wr1f,
    ushort* __restrict__ hl1, ushort* __restrict__ hr1)
{
  __shared__ __align__(16) ushort Bs[32768];   // 64 KB: 2 mats x 2048 granules
  int t = threadIdx.x, w = t>>6, lane = t&63, lq = lane&15, quad = lane>>4;
  int tile = blockIdx.x;
  #pragma unroll
  for (int j=0;j<16;j++){
    int r = w + j*4;
    int m = r>>5, g = r&31;
    const ushort* Wm = m ? Wr1f : Wl1f;
    glds16(Wm + (size_t)g*512 + lane*8, Bs + r*512);
  }
  short8 av[2][4];
  int row0 = tile*128 + w*32;
  #pragma unroll
  for (int mt=0;mt<2;mt++){
    int row = row0 + mt*16 + lq; if (row >= N) row = N-1;
    #pragma unroll
    for (int ks=0;ks<4;ks++)
      av[mt][ks] = *(const short8*)(h + (size_t)row*128 + ks*32 + quad*8);
  }
  __syncthreads();   // drains glds + av loads
  #pragma unroll
  for (int m=0;m<2;m++){
    float4v acc[2][8];
    #pragma unroll
    for (int i=0;i<2;i++)
      #pragma unroll
      for (int j=0;j<8;j++)
        #pragma unroll
        for (int r=0;r<4;r++) acc[i][j][r] = 0.f;
    #pragma unroll
    for (int ks=0;ks<4;ks++){
      #pragma unroll
      for (int nt=0;nt<8;nt++){
        short8 bf = *(const short8*)(Bs + ((m*32 + ks*8 + nt)*64 + lane)*8);
        acc[0][nt] = __builtin_amdgcn_mfma_f32_16x16x32_bf16(av[0][ks], bf, acc[0][nt], 0,0,0);
        acc[1][nt] = __builtin_amdgcn_mfma_f32_16x16x32_bf16(av[1][ks], bf, acc[1][nt], 0,0,0);
      }
    }
    ushort* Ym = m ? hr1 : hl1;
    #pragma unroll
    for (int mt=0;mt<2;mt++){
      #pragma unroll
      for (int r=0;r<4;r++){
        int row = row0 + mt*16 + quad*4 + r;
        if (row < N){
          #pragma unroll
          for (int nt=0;nt<8;nt++)
            Ym[(size_t)row*128 + nt*16 + lq] = f2b(acc[mt][nt][r]);
        }
      }
    }
  }
}

// ================= head: weights-resident + fused W2 dot + alpha mix =================
__global__ __launch_bounds__(256) void head_wres(
    const ushort* __restrict__ h2, int N,
    const ushort* __restrict__ W1f, const float* __restrict__ b1,
    const float* __restrict__ W2, const float* __restrict__ b2,
    const float* __restrict__ alogit, const float* __restrict__ rer,
    float* __restrict__ out)
{
  __shared__ __align__(16) ushort Bs[8192];   // 16 KB: 1024 granules
  int t = threadIdx.x, w = t>>6, lane = t&63, lq = lane&15, quad = lane>>4;
  int tile = blockIdx.x;
  #pragma unroll
  for (int j=0;j<4;j++){
    int r = w + j*4;
    glds16(W1f + (size_t)r*512 + lane*8, Bs + r*512);
  }
  short8 av[2][4];
  int row0 = tile*128 + w*32;
  #pragma unroll
  for (int mt=0;mt<2;mt++){
    int row = row0 + mt*16 + lq; if (row >= N) row = N-1;
    #pragma unroll
    for (int ks=0;ks<4;ks++)
      av[mt][ks] = *(const short8*)(h2 + (size_t)row*128 + ks*32 + quad*8);
  }
  __syncthreads();
  float4v acc[2][4];
  #pragma unroll
  for (int i=0;i<2;i++)
    #pragma unroll
    for (int j=0;j<4;j++)
      #pragma unroll
      for (int r=0;r<4;r++) acc[i][j][r] = 0.f;
  #pragma unroll
  for (int ks=0;ks<4;ks++){
    #pragma unroll
    for (int nt=0;nt<4;nt++){
      short8 bf = *(const short8*)(Bs + ((ks*4 + nt)*64 + lane)*8);
      acc[0][nt] = __builtin_amdgcn_mfma_f32_16x16x32_bf16(av[0][ks], bf, acc[0][nt], 0,0,0);
      acc[1][nt] = __builtin_amdgcn_mfma_f32_16x16x32_bf16(av[1][ks], bf, acc[1][nt], 0,0,0);
    }
  }
  float al = alogit[0];
  float a  = 1.f / (1.f + __expf(-al));
  float pw[2][4] = {{0.f,0.f,0.f,0.f},{0.f,0.f,0.f,0.f}};
  #pragma unroll
  for (int nt=0; nt<4; nt++){
    int c = nt*16 + lq;
    float w2 = W2[c];
    float bb = b1[c];
    #pragma unroll
    for (int mt=0; mt<2; mt++)
      #pragma unroll
      for (int r=0; r<4; r++)
        pw[mt][r] += fmaxf(acc[mt][nt][r] + bb, 0.f) * w2;
  }
  #pragma unroll
  for (int mask=1; mask<16; mask<<=1){
    #pragma unroll
    for (int mt=0; mt<2; mt++)
      #pragma unroll
      for (int r=0; r<4; r++)
        pw[mt][r] += __shfl_xor(pw[mt][r], mask);
  }
  if (lq == 0){
    #pragma unroll
    for (int mt=0; mt<2; mt++)
      #pragma unroll
      for (int r=0; r<4; r++){
        int row = row0 + mt*16 + quad*4 + r;
        if (row < N)
          out[row] = a * rer[row] + (1.f - a) * (pw[mt][r] + b2[0]);
      }
  }
}

// ================= combine: out = bf16(relu(mean_agg + bias + root) + res) =================
__global__ __launch_bounds__(256) void combine_b_kernel(
    const ushort* __restrict__ aggsrc, const ushort* __restrict__ rootsrc,
    const ushort* __restrict__ ressrc, const float* __restrict__ bias,
    const int* __restrict__ off, const int* __restrict__ deg,
    const int* __restrict__ adj, ushort* __restrict__ out, int n)
{
  int t = threadIdx.x;
  int d = t & 63;
  int node = blockIdx.x*4 + (t >> 6);
  if (node >= n) return;
  int s = off[node], e = s + deg[node];
  const unsigned* aggu = (const unsigned*)aggsrc;
  float a0 = 0.f, a1 = 0.f;
  int p = s;
  for (; p+8 <= e; p += 8){
    unsigned v0 = aggu[(size_t)adj[p  ]*64 + d];
    unsigned v1 = aggu[(size_t)adj[p+1]*64 + d];
    unsigned v2 = aggu[(size_t)adj[p+2]*64 + d];
    unsigned v3 = aggu[(size_t)adj[p+3]*64 + d];
    unsigned v4 = aggu[(size_t)adj[p+4]*64 + d];
    unsigned v5 = aggu[(size_t)adj[p+5]*64 + d];
    unsigned v6 = aggu[(size_t)adj[p+6]*64 + d];
    unsigned v7 = aggu[(size_t)adj[p+7]*64 + d];
    a0 += ((blo(v0)+blo(v1)) + (blo(v2)+blo(v3))) + ((blo(v4)+blo(v5)) + (blo(v6)+blo(v7)));
    a1 += ((bhi(v0)+bhi(v1)) + (bhi(v2)+bhi(v3))) + ((bhi(v4)+bhi(v5)) + (bhi(v6)+bhi(v7)));
  }
  for (; p+4 <= e; p += 4){
    unsigned v0 = aggu[(size_t)adj[p  ]*64 + d];
    unsigned v1 = aggu[(size_t)adj[p+1]*64 + d];
    unsigned v2 = aggu[(size_t)adj[p+2]*64 + d];
    unsigned v3 = aggu[(size_t)adj[p+3]*64 + d];
    a0 += (blo(v0)+blo(v1)) + (blo(v2)+blo(v3));
    a1 += (bhi(v0)+bhi(v1)) + (bhi(v2)+bhi(v3));
  }
  for (; p < e; p++){
    unsigned v = aggu[(size_t)adj[p]*64 + d];
    a0 += blo(v); a1 += bhi(v);
  }
  int cnt = e - s;
  float inv = 1.f / (float)((cnt > 1)? cnt : 1);
  unsigned rt = ((const unsigned*)rootsrc)[(size_t)node*64 + d];
  unsigned rs = ((const unsigned*)ressrc)[(size_t)node*64 + d];
  float o0 = fmaxf(a0*inv + bias[2*d]   + blo(rt), 0.f) + blo(rs);
  float o1 = fmaxf(a1*inv + bias[2*d+1] + bhi(rt), 0.f) + bhi(rs);
  ((unsigned*)out)[(size_t)node*64 + d] = (unsigned)f2b(o0) | ((unsigned)f2b(o1) << 16);
}

extern "C" void kernel_launch(void* const* d_in, const int* in_sizes, int n_in,
                              void* d_out, int out_size, void* d_ws, size_t ws_size,
                              hipStream_t stream)
{
  (void)n_in; (void)out_size; (void)ws_size;
  const float* x    = (const float*)d_in[0];
  const int*   ei   = (const int*)d_in[1];
  const float* rer  = (const float*)d_in[2];
  const float* Wp   = (const float*)d_in[3];
  const float* bp   = (const float*)d_in[4];
  const float* Wl0  = (const float*)d_in[5];
  const float* bl0  = (const float*)d_in[6];
  const float* Wr0  = (const float*)d_in[7];
  const float* Wl1  = (const float*)d_in[8];
  const float* bl1  = (const float*)d_in[9];
  const float* Wr1  = (const float*)d_in[10];
  const float* W1   = (const float*)d_in[11];
  const float* b1   = (const float*)d_in[12];
  const float* W2   = (const float*)d_in[13];
  const float* b2   = (const float*)d_in[14];
  const float* alogit = (const float*)d_in[15];

  const int N = in_sizes[2];      // 50000
  const int E = in_sizes[1] / 2;  // 800000
  const int* src = ei;
  const int* dst = ei + E;
  const int NB = (N + NPB - 1) / NPB;        // 98
  const int ntile = (N + 127) / 128;         // 391
  const int nPart = (E + EPB - 1) / EPB;     // 391
  const int nConv = ntile * 16;              // 6256 blocks (ntile*4096 granules)

  // workspace layout
  ushort* U = (ushort*)d_ws;
  ushort* xb  = U;                           // frag-major x: ntile*4096*8
  ushort* xp  = xb + (size_t)ntile*4096*8;   // [N][128]; reused as h2
  ushort* xl0 = xp  + (size_t)N*DH;          // reused as hl1
  ushort* xr0 = xl0 + (size_t)N*DH;          // reused as hr1
  ushort* h   = xr0 + (size_t)N*DH;
  ushort* Wpf  = h + (size_t)N*DH;           // frag-major weights
  ushort* Wl0f = Wpf  + (size_t)4096*8;
  ushort* Wr0f = Wl0f + (size_t)4096*8;
  ushort* Wl1f = Wr0f + (size_t)4096*8;
  ushort* Wr1f = Wl1f + (size_t)2048*8;
  ushort* W1f  = Wr1f + (size_t)2048*8;
  int* I = (int*)(W1f + (size_t)1024*8);
  int* bucketCnt = I;                        // NBMAX
  int* off   = bucketCnt + NBMAX;            // N
  int* deg   = off + N;                      // N
  int* pairS = deg + N;                      // NB*SLOTS
  int* pairD = pairS + (size_t)NB*SLOTS;     // NB*SLOTS
  int* adj   = pairD + (size_t)NB*SLOTS;     // NB*SLOTS

  hipMemsetAsync(bucketCnt, 0, NBMAX*sizeof(int), stream);

  // L1: [partition | convert-x | weight prep]
  fused_front<<<nPart + nConv + 68, 256, 0, stream>>>(
      x, N, xb, Wp, Wl0, Wr0, Wl1, Wr1, W1,
      Wpf, Wl0f, Wr0f, Wl1f, Wr1f, W1f,
      src, dst, E, NB, bucketCnt, pairS, pairD, nPart, nConv);

  // L2: [GEMM0 | bucket_csr]
  fused_gemm0_csr<<<ntile + NB, 256, 0, stream>>>(
      xb, N, ntile, Wpf, Wl0f, Wr0f, bp, xp, xl0, xr0,
      bucketCnt, pairS, pairD, off, deg, adj, NB);

  // combine0: h = relu(mean(xl0[nbrs]) + bl0 + xr0) + xp
  combine_b_kernel<<<(N+3)/4, 256, 0, stream>>>(xl0, xr0, xp, bl0, off, deg, adj, h, N);

  // GEMM1: hl1 = h@Wl1 ; hr1 = h@Wr1
  gemm1_wres<<<ntile, 256, 0, stream>>>(h, N, Wl1f, Wr1f, xl0, xr0);

  // combine1: h2 = relu(mean(hl1[nbrs]) + bl1 + hr1) + h   (h2 -> xp)
  combine_b_kernel<<<(N+3)/4, 256, 0, stream>>>(xl0, xr0, h, bl1, off, deg, adj, xp, N);

  // head: out = a*rer + (1-a)*(relu(xp@W1+b1) . W2 + b2)
  head_wres<<<ntile, 256, 0, stream>>>(xp, N, W1f, b1, W2, b2, alogit, rer, (float*)d_out);
}

// Round 8
// 266.310 us; speedup vs baseline: 1.1688x; 1.1228x over previous
//
#include <hip/hip_runtime.h>
#include <hip/hip_bf16.h>

// SAGE reranker, round 8.
//  - GEMM0: R5's wave-autonomous weights-resident structure (best counters: occ 18%,
//    0 conflicts) with its A-defect fixed: x converted ONCE to bf16 stripe-frag-major
//    (xb, 25.6MB, L3-resident) so the 3x mat-split re-read is cheap; every A-load is a
//    coalesced 1KB wave burst. W 64KB glds->LDS once, ONE barrier, grid-strided stripes.
//  - combine1 fused with head: h2 lives only in LDS (pad stride 272B), MFMA head +
//    W2-dot + alpha-mix in-block; deletes head kernel + 25.6MB h2 round trip.
//  - CSR blocks ride in the GEMM0 launch (LDS union 64KB, CAP=12288).

#define DIN 256
#define DH 128
#define NPB 512
#define NBMAX 128
#define EPB 2048
#define JL (EPB/256)
#define CAP 12288
#define SLOTS 16384

typedef __attribute__((ext_vector_type(8))) short short8;
typedef __attribute__((ext_vector_type(4))) float float4v;

__device__ inline ushort f2b(float f){
  unsigned u = __float_as_uint(f);
  u = (u + 0x7fffu + ((u >> 16) & 1u)) >> 16;   // round-nearest-even
  return (ushort)u;
}
__device__ inline float blo(unsigned v){ return __uint_as_float(v << 16); }
__device__ inline float bhi(unsigned v){ return __uint_as_float(v & 0xffff0000u); }
__device__ inline short8 pack8(float4 f0, float4 f1){
  short8 v;
  v[0]=(short)f2b(f0.x); v[1]=(short)f2b(f0.y); v[2]=(short)f2b(f0.z); v[3]=(short)f2b(f0.w);
  v[4]=(short)f2b(f1.x); v[5]=(short)f2b(f1.y); v[6]=(short)f2b(f1.z); v[7]=(short)f2b(f1.w);
  return v;
}
__device__ inline void glds16(const ushort* g, ushort* l){
  __builtin_amdgcn_global_load_lds((const __attribute__((address_space(1))) void*)g,
                                   (__attribute__((address_space(3))) void*)l, 16, 0, 0);
}

// ================= L1: fused front: [partition | convert-x stripe-frag | weight prep] ===========
__global__ __launch_bounds__(256) void fused_front(
    const float* __restrict__ x, int N, ushort* __restrict__ xb, int nstripe,
    const float* __restrict__ Wp, const float* __restrict__ Wl0, const float* __restrict__ Wr0,
    const float* __restrict__ Wl1, const float* __restrict__ Wr1, const float* __restrict__ W1,
    ushort* __restrict__ Wpf, ushort* __restrict__ Wl0f, ushort* __restrict__ Wr0f,
    ushort* __restrict__ Wl1f, ushort* __restrict__ Wr1f, ushort* __restrict__ W1f,
    const int* __restrict__ src, const int* __restrict__ dst, int E, int NB,
    int* __restrict__ bucketCnt, int* __restrict__ pairS, int* __restrict__ pairD,
    int nPart, int nConv)
{
  __shared__ int hist[NBMAX], lbase[NBMAX], gbase[NBMAX], lcur[NBMAX], sc[NBMAX];
  __shared__ int ls[EPB], ld[EPB];
  int bid = blockIdx.x;
  int t = threadIdx.x;

  if (bid < nPart){
    // ---- partition role ----
    int base = bid * EPB;
    int cntE = E - base; if (cntE > EPB) cntE = EPB;
    for (int i=t;i<NB;i+=256) hist[i]=0;
    __syncthreads();
    int myS[JL], myD[JL];
    #pragma unroll
    for (int j=0;j<JL;j++){
      int e = base + j*256 + t;
      if (e < E){ myS[j]=src[e]; myD[j]=dst[e]; atomicAdd(&hist[myD[j]>>9],1); }
      else myD[j] = -1;
    }
    __syncthreads();
    if (t < NBMAX) sc[t] = (t < NB)? hist[t] : 0;
    __syncthreads();
    for (int st=1; st<NBMAX; st<<=1){
      int v = 0;
      if (t < NBMAX && t >= st) v = sc[t-st];
      __syncthreads();
      if (t < NBMAX) sc[t] += v;
      __syncthreads();
    }
    if (t < NB){
      int excl = (t>0)? sc[t-1] : 0;
      lbase[t] = excl; lcur[t] = excl;
      gbase[t] = atomicAdd(&bucketCnt[t], hist[t]);
    }
    __syncthreads();
    #pragma unroll
    for (int j=0;j<JL;j++){
      if (myD[j] >= 0){
        int b = myD[j] >> 9;
        int p = atomicAdd(&lcur[b], 1);
        ls[p] = myS[j]; ld[p] = myD[j];
      }
    }
    __syncthreads();
    for (int i=t;i<cntE;i+=256){
      int d = ld[i];
      int b = d >> 9;
      int p = gbase[b] + (i - lbase[b]);
      if (p < SLOTS){
        pairS[(size_t)b*SLOTS + p] = ls[i];
        pairD[(size_t)b*SLOTS + p] = d;
      }
    }
  } else if (bid < nPart + nConv){
    // ---- convert role: x fp32 -> xb bf16 stripe-frag-major ----
    // slot gi: L=gi&63, ks=(gi>>6)&7, stripe=gi>>9.
    // holds A[row=stripe*16+(L&15)][k=ks*32+(L>>4)*8 .. +8]
    int gi = (bid - nPart)*256 + t;
    if (gi < nstripe*512){
      int L = gi & 63, ks = (gi>>6)&7, s = gi>>9;
      int row = s*16 + (L&15);
      int k = ks*32 + (L>>4)*8;
      short8 v;
      if (row < N){
        const float* p = x + (size_t)row*DIN + k;
        v = pack8(*(const float4*)p, *(const float4*)(p+4));
      } else {
        #pragma unroll
        for (int j=0;j<8;j++) v[j]=0;
      }
      *(short8*)(xb + (size_t)gi*8) = v;
    }
  } else {
    // ---- prep role: weights -> B-frag-major bf16 ----
    int gi = (bid - nPart - nConv)*256 + t;   // 0..17407
    if (gi < 17408){
      const float* sw; ushort* dw; int cols, b0;
      if      (gi <  4096){ sw=Wp;  dw=Wpf;  cols=128; b0=0; }
      else if (gi <  8192){ sw=Wl0; dw=Wl0f; cols=128; b0=4096; }
      else if (gi < 12288){ sw=Wr0; dw=Wr0f; cols=128; b0=8192; }
      else if (gi < 14336){ sw=Wl1; dw=Wl1f; cols=128; b0=12288; }
      else if (gi < 16384){ sw=Wr1; dw=Wr1f; cols=128; b0=14336; }
      else                { sw=W1;  dw=W1f;  cols=64;  b0=16384; }
      int i = gi - b0;
      int ln = i & 63, g = i >> 6;
      int ntq = cols >> 4;
      int nt = g % ntq, ks = g / ntq;
      int col = nt*16 + (ln & 15);
      int k0 = ks*32 + (ln >> 4)*8;
      short8 v;
      #pragma unroll
      for (int j=0;j<8;j++) v[j] = (short)f2b(sw[(size_t)(k0+j)*cols + col]);
      *(short8*)(dw + (size_t)i*8) = v;
    }
  }
}

// ================= L2: [GEMM0 wres stripe-autonomous | bucket_csr] =================
__global__ __launch_bounds__(256) void gemm0_csr(
    const ushort* __restrict__ xb, int N, int nstripe, int ngemm,
    const ushort* __restrict__ Wpf, const ushort* __restrict__ Wl0f, const ushort* __restrict__ Wr0f,
    const float* __restrict__ bp,
    ushort* __restrict__ xp, ushort* __restrict__ xl0, ushort* __restrict__ xr0,
    const int* __restrict__ bucketCnt, const int* __restrict__ pairS, const int* __restrict__ pairD,
    int* __restrict__ off, int* __restrict__ deg, int* __restrict__ adj)
{
  __shared__ __align__(16) ushort smem[32768];   // 64 KB union
  int bid = blockIdx.x, t = threadIdx.x;

  if (bid < ngemm){
    // ---- GEMM0 role: mat-split, W resident in LDS, stripes grid-strided ----
    int mat = bid % 3, b = bid / 3;          // 256 blocks per mat, L2-interleaved
    int nblk = ngemm / 3;
    const ushort* Wf = (mat==0)? Wpf : (mat==1)? Wl0f : Wr0f;
    ushort* Y        = (mat==0)? xp  : (mat==1)? xl0  : xr0;
    int w = t>>6, lane = t&63, lq = lane&15, quad = lane>>4;
    #pragma unroll
    for (int j=0;j<16;j++){
      int g = w + j*4;                       // 64 wave-bursts x 1KB = 64KB
      glds16(Wf + (size_t)g*512 + lane*8, smem + g*512);
    }
    __syncthreads();                          // the only barrier
    float bias[8];
    #pragma unroll
    for (int nt=0;nt<8;nt++) bias[nt] = (mat==0)? bp[nt*16 + lq] : 0.f;
    int nchunk = (nstripe + 3) >> 2;
    for (int c = b; c < nchunk; c += nblk){
      int stripe = c*4 + w;
      int row0 = stripe*16;
      if (row0 >= N) continue;
      short8 av[8];
      #pragma unroll
      for (int ks=0;ks<8;ks++)
        av[ks] = *(const short8*)(xb + ((size_t)stripe*8 + ks)*512 + lane*8);
      float4v acc[8];
      #pragma unroll
      for (int nt=0;nt<8;nt++)
        #pragma unroll
        for (int r=0;r<4;r++) acc[nt][r] = 0.f;
      #pragma unroll
      for (int ks=0;ks<8;ks++){
        #pragma unroll
        for (int nt=0;nt<8;nt++){
          short8 bf = *(const short8*)(smem + (size_t)((ks*8 + nt)*64 + lane)*8);
          acc[nt] = __builtin_amdgcn_mfma_f32_16x16x32_bf16(av[ks], bf, acc[nt], 0,0,0);
        }
      }
      #pragma unroll
      for (int nt=0;nt<8;nt++){
        #pragma unroll
        for (int r=0;r<4;r++){
          int row = row0 + quad*4 + r;
          if (row < N)
            Y[(size_t)row*128 + nt*16 + lq] = f2b(acc[nt][r] + bias[nt]);
        }
      }
    }
  } else {
    // ---- bucket_csr role ----
    int b = bid - ngemm;
    int* cnt  = (int*)smem;            // 512
    int* offl = cnt + NPB;             // 513
    int* s1   = offl + NPB + 1;        // 256
    int* win  = s1 + 256;              // CAP=12288  (total 54.3 KB < 64 KB)
    int node0 = b * NPB;
    int base  = b * SLOTS;
    int ce = bucketCnt[b]; if (ce > SLOTS) ce = SLOTS;
    for (int i=t;i<NPB;i+=256) cnt[i]=0;
    __syncthreads();
    for (int i=t;i<ce;i+=256) atomicAdd(&cnt[pairD[(size_t)base+i]-node0], 1);
    __syncthreads();
    int a0 = cnt[2*t], a1 = cnt[2*t+1];
    s1[t] = a0 + a1;
    __syncthreads();
    for (int st=1; st<256; st<<=1){
      int v = (t>=st)? s1[t-st] : 0;
      __syncthreads();
      s1[t] += v;
      __syncthreads();
    }
    int excl = (t>0)? s1[t-1] : 0;
    offl[2*t] = excl; offl[2*t+1] = excl + a0;
    __syncthreads();
    for (int i=t;i<NPB;i+=256){
      int node = node0 + i;
      if (node < N){ off[node] = base + offl[i]; deg[node] = cnt[i]; }
    }
    __syncthreads();
    if (ce <= CAP){
      for (int i=t;i<ce;i+=256){
        int d = pairD[(size_t)base+i];
        int p = atomicAdd(&offl[d-node0], 1);
        win[p] = pairS[(size_t)base+i];
      }
      __syncthreads();
      for (int i=t;i<ce;i+=256) adj[(size_t)base+i] = win[i];
    } else {
      for (int i=t;i<ce;i+=256){
        int d = pairD[(size_t)base+i];
        int p = atomicAdd(&offl[d-node0], 1);
        adj[(size_t)base+p] = pairS[(size_t)base+i];
      }
    }
  }
}

// ================= combine0: h = bf16(relu(mean_agg + bias + root) + res) =================
__global__ __launch_bounds__(256) void combine_b_kernel(
    const ushort* __restrict__ aggsrc, const ushort* __restrict__ rootsrc,
    const ushort* __restrict__ ressrc, const float* __restrict__ bias,
    const int* __restrict__ off, const int* __restrict__ deg,
    const int* __restrict__ adj, ushort* __restrict__ out, int n)
{
  int t = threadIdx.x;
  int d = t & 63;
  int node = blockIdx.x*4 + (t >> 6);
  if (node >= n) return;
  int s = off[node], e = s + deg[node];
  const unsigned* aggu = (const unsigned*)aggsrc;
  float a0 = 0.f, a1 = 0.f;
  int p = s;
  for (; p+8 <= e; p += 8){
    unsigned v0 = aggu[(size_t)adj[p  ]*64 + d];
    unsigned v1 = aggu[(size_t)adj[p+1]*64 + d];
    unsigned v2 = aggu[(size_t)adj[p+2]*64 + d];
    unsigned v3 = aggu[(size_t)adj[p+3]*64 + d];
    unsigned v4 = aggu[(size_t)adj[p+4]*64 + d];
    unsigned v5 = aggu[(size_t)adj[p+5]*64 + d];
    unsigned v6 = aggu[(size_t)adj[p+6]*64 + d];
    unsigned v7 = aggu[(size_t)adj[p+7]*64 + d];
    a0 += ((blo(v0)+blo(v1)) + (blo(v2)+blo(v3))) + ((blo(v4)+blo(v5)) + (blo(v6)+blo(v7)));
    a1 += ((bhi(v0)+bhi(v1)) + (bhi(v2)+bhi(v3))) + ((bhi(v4)+bhi(v5)) + (bhi(v6)+bhi(v7)));
  }
  for (; p+4 <= e; p += 4){
    unsigned v0 = aggu[(size_t)adj[p  ]*64 + d];
    unsigned v1 = aggu[(size_t)adj[p+1]*64 + d];
    unsigned v2 = aggu[(size_t)adj[p+2]*64 + d];
    unsigned v3 = aggu[(size_t)adj[p+3]*64 + d];
    a0 += (blo(v0)+blo(v1)) + (blo(v2)+blo(v3));
    a1 += (bhi(v0)+bhi(v1)) + (bhi(v2)+bhi(v3));
  }
  for (; p < e; p++){
    unsigned v = aggu[(size_t)adj[p]*64 + d];
    a0 += blo(v); a1 += bhi(v);
  }
  int cnt = e - s;
  float inv = 1.f / (float)((cnt > 1)? cnt : 1);
  unsigned rt = ((const unsigned*)rootsrc)[(size_t)node*64 + d];
  unsigned rs = ((const unsigned*)ressrc)[(size_t)node*64 + d];
  float o0 = fmaxf(a0*inv + bias[2*d]   + blo(rt), 0.f) + blo(rs);
  float o1 = fmaxf(a1*inv + bias[2*d+1] + bhi(rt), 0.f) + bhi(rs);
  ((unsigned*)out)[(size_t)node*64 + d] = (unsigned)f2b(o0) | ((unsigned)f2b(o1) << 16);
}

// ================= GEMM1: weights-resident, one barrier (R7, unchanged) =================
__global__ __launch_bounds__(256) void gemm1_wres(
    const ushort* __restrict__ h, int N,
    const ushort* __restrict__ Wl1f, const ushort* __restrict__ Wr1f,
    ushort* __restrict__ hl1, ushort* __restrict__ hr1)
{
  __shared__ __align__(16) ushort Bs[32768];
  int t = threadIdx.x, w = t>>6, lane = t&63, lq = lane&15, quad = lane>>4;
  int tile = blockIdx.x;
  #pragma unroll
  for (int j=0;j<16;j++){
    int r = w + j*4;
    int m = r>>5, g = r&31;
    const ushort* Wm = m ? Wr1f : Wl1f;
    glds16(Wm + (size_t)g*512 + lane*8, Bs + r*512);
  }
  short8 av[2][4];
  int row0 = tile*128 + w*32;
  #pragma unroll
  for (int mt=0;mt<2;mt++){
    int row = row0 + mt*16 + lq; if (row >= N) row = N-1;
    #pragma unroll
    for (int ks=0;ks<4;ks++)
      av[mt][ks] = *(const short8*)(h + (size_t)row*128 + ks*32 + quad*8);
  }
  __syncthreads();
  #pragma unroll
  for (int m=0;m<2;m++){
    float4v acc[2][8];
    #pragma unroll
    for (int i=0;i<2;i++)
      #pragma unroll
      for (int j=0;j<8;j++)
        #pragma unroll
        for (int r=0;r<4;r++) acc[i][j][r] = 0.f;
    #pragma unroll
    for (int ks=0;ks<4;ks++){
      #pragma unroll
      for (int nt=0;nt<8;nt++){
        short8 bf = *(const short8*)(Bs + ((m*32 + ks*8 + nt)*64 + lane)*8);
        acc[0][nt] = __builtin_amdgcn_mfma_f32_16x16x32_bf16(av[0][ks], bf, acc[0][nt], 0,0,0);
        acc[1][nt] = __builtin_amdgcn_mfma_f32_16x16x32_bf16(av[1][ks], bf, acc[1][nt], 0,0,0);
      }
    }
    ushort* Ym = m ? hr1 : hl1;
    #pragma unroll
    for (int mt=0;mt<2;mt++){
      #pragma unroll
      for (int r=0;r<4;r++){
        int row = row0 + mt*16 + quad*4 + r;
        if (row < N){
          #pragma unroll
          for (int nt=0;nt<8;nt++)
            Ym[(size_t)row*128 + nt*16 + lq] = f2b(acc[mt][nt][r]);
        }
      }
    }
  }
}

// ================= combine1 + head fused =================
// Block = 16 nodes. Phase 1: gather -> h2 rows in LDS (stride 272B, 2-way free).
// Phase 2: all waves redundantly MFMA s1=relu(h2@W1+b1), dot W2, alpha-mix; each
// wave stores its 4 rows. h2 never touches global memory.
__global__ __launch_bounds__(256) void combine1_head(
    const ushort* __restrict__ hl1, const ushort* __restrict__ hr1,
    const ushort* __restrict__ h, const float* __restrict__ bl1,
    const int* __restrict__ off, const int* __restrict__ deg, const int* __restrict__ adj,
    const ushort* __restrict__ W1f, const float* __restrict__ b1,
    const float* __restrict__ W2, const float* __restrict__ b2,
    const float* __restrict__ alogit, const float* __restrict__ rer,
    float* __restrict__ out, int n)
{
  __shared__ __align__(16) ushort W1s[8192];      // 16 KB frag-packed W1
  __shared__ __align__(16) ushort h2s[16*136];    // 16 rows x 272B (padded)
  int t = threadIdx.x, w = t>>6, lane = t&63, lq = lane&15, quad = lane>>4;
  #pragma unroll
  for (int j=0;j<4;j++){
    int g = w + j*4;
    glds16(W1f + (size_t)g*512 + lane*8, W1s + g*512);
  }
  int node0 = blockIdx.x*16;
  unsigned* h2u = (unsigned*)h2s;                 // row stride 68 uints
  const unsigned* aggu = (const unsigned*)hl1;
  #pragma unroll
  for (int j=0;j<4;j++){
    int node = node0 + w*4 + j;
    float o0 = 0.f, o1 = 0.f;
    if (node < n){
      int s = off[node], e = s + deg[node];
      float a0 = 0.f, a1 = 0.f;
      int p = s;
      for (; p+8 <= e; p += 8){
        unsigned v0 = aggu[(size_t)adj[p  ]*64 + lane];
        unsigned v1 = aggu[(size_t)adj[p+1]*64 + lane];
        unsigned v2 = aggu[(size_t)adj[p+2]*64 + lane];
        unsigned v3 = aggu[(size_t)adj[p+3]*64 + lane];
        unsigned v4 = aggu[(size_t)adj[p+4]*64 + lane];
        unsigned v5 = aggu[(size_t)adj[p+5]*64 + lane];
        unsigned v6 = aggu[(size_t)adj[p+6]*64 + lane];
        unsigned v7 = aggu[(size_t)adj[p+7]*64 + lane];
        a0 += ((blo(v0)+blo(v1)) + (blo(v2)+blo(v3))) + ((blo(v4)+blo(v5)) + (blo(v6)+blo(v7)));
        a1 += ((bhi(v0)+bhi(v1)) + (bhi(v2)+bhi(v3))) + ((bhi(v4)+bhi(v5)) + (bhi(v6)+bhi(v7)));
      }
      for (; p < e; p++){
        unsigned v = aggu[(size_t)adj[p]*64 + lane];
        a0 += blo(v); a1 += bhi(v);
      }
      int cnt = e - s;
      float inv = 1.f / (float)((cnt > 1)? cnt : 1);
      unsigned rt = ((const unsigned*)hr1)[(size_t)node*64 + lane];
      unsigned rs = ((const unsigned*)h)[(size_t)node*64 + lane];
      o0 = fmaxf(a0*inv + bl1[2*lane]   + blo(rt), 0.f) + blo(rs);
      o1 = fmaxf(a1*inv + bl1[2*lane+1] + bhi(rt), 0.f) + bhi(rs);
    }
    h2u[(w*4+j)*68 + lane] = (unsigned)f2b(o0) | ((unsigned)f2b(o1) << 16);
  }
  __syncthreads();   // drains glds + LDS writes

  short8 av[4];
  #pragma unroll
  for (int ks=0;ks<4;ks++)
    av[ks] = *(const short8*)(h2s + lq*136 + ks*32 + quad*8);
  float4v acc[4];
  #pragma unroll
  for (int nt=0;nt<4;nt++)
    #pragma unroll
    for (int r=0;r<4;r++) acc[nt][r] = 0.f;
  #pragma unroll
  for (int ks=0;ks<4;ks++){
    #pragma unroll
    for (int nt=0;nt<4;nt++){
      short8 bf = *(const short8*)(W1s + ((ks*4 + nt)*64 + lane)*8);
      acc[nt] = __builtin_amdgcn_mfma_f32_16x16x32_bf16(av[ks], bf, acc[nt], 0,0,0);
    }
  }
  float al = alogit[0];
  float a  = 1.f / (1.f + __expf(-al));
  float pw[4] = {0.f,0.f,0.f,0.f};
  #pragma unroll
  for (int nt=0; nt<4; nt++){
    int c = nt*16 + lq;
    float w2 = W2[c];
    float bb = b1[c];
    #pragma unroll
    for (int r=0; r<4; r++)
      pw[r] += fmaxf(acc[nt][r] + bb, 0.f) * w2;
  }
  #pragma unroll
  for (int mask=1; mask<16; mask<<=1){
    #pragma unroll
    for (int r=0; r<4; r++)
      pw[r] += __shfl_xor(pw[r], mask);
  }
  if (lq == 0){
    #pragma unroll
    for (int r=0; r<4; r++){
      int rl = quad*4 + r;
      if ((rl >> 2) == w){                        // each wave stores its 4 rows
        int node = node0 + rl;
        if (node < n)
          out[node] = a * rer[node] + (1.f - a) * (pw[r] + b2[0]);
      }
    }
  }
}

extern "C" void kernel_launch(void* const* d_in, const int* in_sizes, int n_in,
                              void* d_out, int out_size, void* d_ws, size_t ws_size,
                              hipStream_t stream)
{
  (void)n_in; (void)out_size; (void)ws_size;
  const float* x    = (const float*)d_in[0];
  const int*   ei   = (const int*)d_in[1];
  const float* rer  = (const float*)d_in[2];
  const float* Wp   = (const float*)d_in[3];
  const float* bp   = (const float*)d_in[4];
  const float* Wl0  = (const float*)d_in[5];
  const float* bl0  = (const float*)d_in[6];
  const float* Wr0  = (const float*)d_in[7];
  const float* Wl1  = (const float*)d_in[8];
  const float* bl1  = (const float*)d_in[9];
  const float* Wr1  = (const float*)d_in[10];
  const float* W1   = (const float*)d_in[11];
  const float* b1   = (const float*)d_in[12];
  const float* W2   = (const float*)d_in[13];
  const float* b2   = (const float*)d_in[14];
  const float* alogit = (const float*)d_in[15];

  const int N = in_sizes[2];      // 50000
  const int E = in_sizes[1] / 2;  // 800000
  const int* src = ei;
  const int* dst = ei + E;
  const int NB = (N + NPB - 1) / NPB;        // 98
  const int nstripe = (N + 15) / 16;         // 3125
  const int ntile = (N + 127) / 128;         // 391
  const int nPart = (E + EPB - 1) / EPB;     // 391
  const int nConv = (nstripe*512 + 255)/256; // 6250

  // workspace layout
  ushort* U = (ushort*)d_ws;
  ushort* xb  = U;                           // stripe-frag x: nstripe*512*8
  ushort* xp  = xb + (size_t)nstripe*512*8;  // [N][128]
  ushort* xl0 = xp  + (size_t)N*DH;          // reused as hl1
  ushort* xr0 = xl0 + (size_t)N*DH;          // reused as hr1
  ushort* h   = xr0 + (size_t)N*DH;
  ushort* Wpf  = h + (size_t)N*DH;           // frag-major weights
  ushort* Wl0f = Wpf  + (size_t)4096*8;
  ushort* Wr0f = Wl0f + (size_t)4096*8;
  ushort* Wl1f = Wr0f + (size_t)4096*8;
  ushort* Wr1f = Wl1f + (size_t)2048*8;
  ushort* W1f  = Wr1f + (size_t)2048*8;
  int* I = (int*)(W1f + (size_t)1024*8);
  int* bucketCnt = I;                        // NBMAX
  int* off   = bucketCnt + NBMAX;            // N
  int* deg   = off + N;                      // N
  int* pairS = deg + N;                      // NB*SLOTS
  int* pairD = pairS + (size_t)NB*SLOTS;     // NB*SLOTS
  int* adj   = pairD + (size_t)NB*SLOTS;     // NB*SLOTS

  hipMemsetAsync(bucketCnt, 0, NBMAX*sizeof(int), stream);

  // L1: [partition | convert | prep]
  fused_front<<<nPart + nConv + 68, 256, 0, stream>>>(
      x, N, xb, nstripe, Wp, Wl0, Wr0, Wl1, Wr1, W1,
      Wpf, Wl0f, Wr0f, Wl1f, Wr1f, W1f,
      src, dst, E, NB, bucketCnt, pairS, pairD, nPart, nConv);

  // L2: [GEMM0 (wres stripes) | bucket_csr]
  gemm0_csr<<<768 + NB, 256, 0, stream>>>(
      xb, N, nstripe, 768, Wpf, Wl0f, Wr0f, bp, xp, xl0, xr0,
      bucketCnt, pairS, pairD, off, deg, adj);

  // combine0: h = relu(mean(xl0[nbrs]) + bl0 + xr0) + xp
  combine_b_kernel<<<(N+3)/4, 256, 0, stream>>>(xl0, xr0, xp, bl0, off, deg, adj, h, N);

  // GEMM1: hl1 = h@Wl1 ; hr1 = h@Wr1
  gemm1_wres<<<ntile, 256, 0, stream>>>(h, N, Wl1f, Wr1f, xl0, xr0);

  // combine1+head fused: out = a*rer + (1-a)*(relu(h2@W1+b1).W2 + b2), h2 LDS-only
  combine1_head<<<(N+15)/16, 256, 0, stream>>>(
      xl0, xr0, h, bl1, off, deg, adj, W1f, b1, W2, b2, alogit, rer, (float*)d_out, N);
}

// Round 9
// 258.606 us; speedup vs baseline: 1.2037x; 1.0298x over previous
//
#include <hip/hip_runtime.h>
#include <hip/hip_bf16.h>

// SAGE reranker, round 9: fp8 gather operands + 16-deep gather MLP.
// R8 profile: combine1_head 51us, FETCH 91MB vs 12.8MB gathered array -> random
// row-gather misses per-XCD L2 (4MB), L3-fabric-bound at 1.8 TB/s. Fix: the
// aggregated projections (xl0, hl1) are stored as fp8 e4m3 (HW cvt in GEMM
// epilogues): row 256->128B, array 12.8->6.4MB. Gather unroll 8->16.
// Root/residual stay bf16; fp8 error enters only via the 16-way mean.

#define DIN 256
#define DH 128
#define NPB 512
#define NBMAX 128
#define EPB 2048
#define JL (EPB/256)
#define CAP 12288
#define SLOTS 16384

typedef __attribute__((ext_vector_type(8))) short short8;
typedef __attribute__((ext_vector_type(4))) float float4v;
typedef __attribute__((ext_vector_type(2))) float float2v;

__device__ inline ushort f2b(float f){
  unsigned u = __float_as_uint(f);
  u = (u + 0x7fffu + ((u >> 16) & 1u)) >> 16;   // round-nearest-even
  return (ushort)u;
}
__device__ inline float blo(unsigned v){ return __uint_as_float(v << 16); }
__device__ inline float bhi(unsigned v){ return __uint_as_float(v & 0xffff0000u); }
__device__ inline short8 pack8(float4 f0, float4 f1){
  short8 v;
  v[0]=(short)f2b(f0.x); v[1]=(short)f2b(f0.y); v[2]=(short)f2b(f0.z); v[3]=(short)f2b(f0.w);
  v[4]=(short)f2b(f1.x); v[5]=(short)f2b(f1.y); v[6]=(short)f2b(f1.z); v[7]=(short)f2b(f1.w);
  return v;
}
__device__ inline void glds16(const ushort* g, ushort* l){
  __builtin_amdgcn_global_load_lds((const __attribute__((address_space(1))) void*)g,
                                   (__attribute__((address_space(3))) void*)l, 16, 0, 0);
}
// fp8 e4m3 (OCP on gfx950) encode/decode via HW converts
__device__ inline unsigned char enc8(float v){
  return (unsigned char)(__builtin_amdgcn_cvt_pk_fp8_f32(v, v, 0, false) & 0xFF);
}
__device__ inline float2v dec8(unsigned u){
  return __builtin_amdgcn_cvt_pk_f32_fp8((int)u, false);   // decodes low 2 bytes
}

// ================= L1: fused front: [partition | convert-x stripe-frag | weight prep] ===========
__global__ __launch_bounds__(256) void fused_front(
    const float* __restrict__ x, int N, ushort* __restrict__ xb, int nstripe,
    const float* __restrict__ Wp, const float* __restrict__ Wl0, const float* __restrict__ Wr0,
    const float* __restrict__ Wl1, const float* __restrict__ Wr1, const float* __restrict__ W1,
    ushort* __restrict__ Wpf, ushort* __restrict__ Wl0f, ushort* __restrict__ Wr0f,
    ushort* __restrict__ Wl1f, ushort* __restrict__ Wr1f, ushort* __restrict__ W1f,
    const int* __restrict__ src, const int* __restrict__ dst, int E, int NB,
    int* __restrict__ bucketCnt, int* __restrict__ pairS, int* __restrict__ pairD,
    int nPart, int nConv)
{
  __shared__ int hist[NBMAX], lbase[NBMAX], gbase[NBMAX], lcur[NBMAX], sc[NBMAX];
  __shared__ int ls[EPB], ld[EPB];
  int bid = blockIdx.x;
  int t = threadIdx.x;

  if (bid < nPart){
    int base = bid * EPB;
    int cntE = E - base; if (cntE > EPB) cntE = EPB;
    for (int i=t;i<NB;i+=256) hist[i]=0;
    __syncthreads();
    int myS[JL], myD[JL];
    #pragma unroll
    for (int j=0;j<JL;j++){
      int e = base + j*256 + t;
      if (e < E){ myS[j]=src[e]; myD[j]=dst[e]; atomicAdd(&hist[myD[j]>>9],1); }
      else myD[j] = -1;
    }
    __syncthreads();
    if (t < NBMAX) sc[t] = (t < NB)? hist[t] : 0;
    __syncthreads();
    for (int st=1; st<NBMAX; st<<=1){
      int v = 0;
      if (t < NBMAX && t >= st) v = sc[t-st];
      __syncthreads();
      if (t < NBMAX) sc[t] += v;
      __syncthreads();
    }
    if (t < NB){
      int excl = (t>0)? sc[t-1] : 0;
      lbase[t] = excl; lcur[t] = excl;
      gbase[t] = atomicAdd(&bucketCnt[t], hist[t]);
    }
    __syncthreads();
    #pragma unroll
    for (int j=0;j<JL;j++){
      if (myD[j] >= 0){
        int b = myD[j] >> 9;
        int p = atomicAdd(&lcur[b], 1);
        ls[p] = myS[j]; ld[p] = myD[j];
      }
    }
    __syncthreads();
    for (int i=t;i<cntE;i+=256){
      int d = ld[i];
      int b = d >> 9;
      int p = gbase[b] + (i - lbase[b]);
      if (p < SLOTS){
        pairS[(size_t)b*SLOTS + p] = ls[i];
        pairD[(size_t)b*SLOTS + p] = d;
      }
    }
  } else if (bid < nPart + nConv){
    int gi = (bid - nPart)*256 + t;
    if (gi < nstripe*512){
      int L = gi & 63, ks = (gi>>6)&7, s = gi>>9;
      int row = s*16 + (L&15);
      int k = ks*32 + (L>>4)*8;
      short8 v;
      if (row < N){
        const float* p = x + (size_t)row*DIN + k;
        v = pack8(*(const float4*)p, *(const float4*)(p+4));
      } else {
        #pragma unroll
        for (int j=0;j<8;j++) v[j]=0;
      }
      *(short8*)(xb + (size_t)gi*8) = v;
    }
  } else {
    int gi = (bid - nPart - nConv)*256 + t;
    if (gi < 17408){
      const float* sw; ushort* dw; int cols, b0;
      if      (gi <  4096){ sw=Wp;  dw=Wpf;  cols=128; b0=0; }
      else if (gi <  8192){ sw=Wl0; dw=Wl0f; cols=128; b0=4096; }
      else if (gi < 12288){ sw=Wr0; dw=Wr0f; cols=128; b0=8192; }
      else if (gi < 14336){ sw=Wl1; dw=Wl1f; cols=128; b0=12288; }
      else if (gi < 16384){ sw=Wr1; dw=Wr1f; cols=128; b0=14336; }
      else                { sw=W1;  dw=W1f;  cols=64;  b0=16384; }
      int i = gi - b0;
      int ln = i & 63, g = i >> 6;
      int ntq = cols >> 4;
      int nt = g % ntq, ks = g / ntq;
      int col = nt*16 + (ln & 15);
      int k0 = ks*32 + (ln >> 4)*8;
      short8 v;
      #pragma unroll
      for (int j=0;j<8;j++) v[j] = (short)f2b(sw[(size_t)(k0+j)*cols + col]);
      *(short8*)(dw + (size_t)i*8) = v;
    }
  }
}

// ================= L2: [GEMM0 wres | bucket_csr]; mat1 (xl0) output is fp8 =================
__global__ __launch_bounds__(256) void gemm0_csr(
    const ushort* __restrict__ xb, int N, int nstripe, int ngemm,
    const ushort* __restrict__ Wpf, const ushort* __restrict__ Wl0f, const ushort* __restrict__ Wr0f,
    const float* __restrict__ bp,
    ushort* __restrict__ xp, unsigned char* __restrict__ q8, ushort* __restrict__ xr0,
    const int* __restrict__ bucketCnt, const int* __restrict__ pairS, const int* __restrict__ pairD,
    int* __restrict__ off, int* __restrict__ deg, int* __restrict__ adj)
{
  __shared__ __align__(16) ushort smem[32768];
  int bid = blockIdx.x, t = threadIdx.x;

  if (bid < ngemm){
    int mat = bid % 3, b = bid / 3;
    int nblk = ngemm / 3;
    const ushort* Wf = (mat==0)? Wpf : (mat==1)? Wl0f : Wr0f;
    int w = t>>6, lane = t&63, lq = lane&15, quad = lane>>4;
    #pragma unroll
    for (int j=0;j<16;j++){
      int g = w + j*4;
      glds16(Wf + (size_t)g*512 + lane*8, smem + g*512);
    }
    __syncthreads();
    float bias[8];
    #pragma unroll
    for (int nt=0;nt<8;nt++) bias[nt] = (mat==0)? bp[nt*16 + lq] : 0.f;
    int nchunk = (nstripe + 3) >> 2;
    for (int c = b; c < nchunk; c += nblk){
      int stripe = c*4 + w;
      int row0 = stripe*16;
      if (row0 >= N) continue;
      short8 av[8];
      #pragma unroll
      for (int ks=0;ks<8;ks++)
        av[ks] = *(const short8*)(xb + ((size_t)stripe*8 + ks)*512 + lane*8);
      float4v acc[8];
      #pragma unroll
      for (int nt=0;nt<8;nt++)
        #pragma unroll
        for (int r=0;r<4;r++) acc[nt][r] = 0.f;
      #pragma unroll
      for (int ks=0;ks<8;ks++){
        #pragma unroll
        for (int nt=0;nt<8;nt++){
          short8 bf = *(const short8*)(smem + (size_t)((ks*8 + nt)*64 + lane)*8);
          acc[nt] = __builtin_amdgcn_mfma_f32_16x16x32_bf16(av[ks], bf, acc[nt], 0,0,0);
        }
      }
      if (mat == 1){
        #pragma unroll
        for (int nt=0;nt<8;nt++)
          #pragma unroll
          for (int r=0;r<4;r++){
            int row = row0 + quad*4 + r;
            if (row < N) q8[(size_t)row*128 + nt*16 + lq] = enc8(acc[nt][r]);
          }
      } else {
        ushort* Y = (mat==0)? xp : xr0;
        #pragma unroll
        for (int nt=0;nt<8;nt++)
          #pragma unroll
          for (int r=0;r<4;r++){
            int row = row0 + quad*4 + r;
            if (row < N) Y[(size_t)row*128 + nt*16 + lq] = f2b(acc[nt][r] + bias[nt]);
          }
      }
    }
  } else {
    int b = bid - ngemm;
    int* cnt  = (int*)smem;
    int* offl = cnt + NPB;
    int* s1   = offl + NPB + 1;
    int* win  = s1 + 256;
    int node0 = b * NPB;
    int base  = b * SLOTS;
    int ce = bucketCnt[b]; if (ce > SLOTS) ce = SLOTS;
    for (int i=t;i<NPB;i+=256) cnt[i]=0;
    __syncthreads();
    for (int i=t;i<ce;i+=256) atomicAdd(&cnt[pairD[(size_t)base+i]-node0], 1);
    __syncthreads();
    int a0 = cnt[2*t], a1 = cnt[2*t+1];
    s1[t] = a0 + a1;
    __syncthreads();
    for (int st=1; st<256; st<<=1){
      int v = (t>=st)? s1[t-st] : 0;
      __syncthreads();
      s1[t] += v;
      __syncthreads();
    }
    int excl = (t>0)? s1[t-1] : 0;
    offl[2*t] = excl; offl[2*t+1] = excl + a0;
    __syncthreads();
    for (int i=t;i<NPB;i+=256){
      int node = node0 + i;
      if (node < N){ off[node] = base + offl[i]; deg[node] = cnt[i]; }
    }
    __syncthreads();
    if (ce <= CAP){
      for (int i=t;i<ce;i+=256){
        int d = pairD[(size_t)base+i];
        int p = atomicAdd(&offl[d-node0], 1);
        win[p] = pairS[(size_t)base+i];
      }
      __syncthreads();
      for (int i=t;i<ce;i+=256) adj[(size_t)base+i] = win[i];
    } else {
      for (int i=t;i<ce;i+=256){
        int d = pairD[(size_t)base+i];
        int p = atomicAdd(&offl[d-node0], 1);
        adj[(size_t)base+p] = pairS[(size_t)base+i];
      }
    }
  }
}

// ================= combine0: h = bf16(relu(mean_fp8_agg + bias + root) + res) =================
// wave per node; lane d owns dims 2d,2d+1 (fp8 pair = ushort). 16-deep gather MLP.
__global__ __launch_bounds__(256) void combine0_f8(
    const unsigned char* __restrict__ agg8, const ushort* __restrict__ rootsrc,
    const ushort* __restrict__ ressrc, const float* __restrict__ bias,
    const int* __restrict__ off, const int* __restrict__ deg,
    const int* __restrict__ adj, ushort* __restrict__ out, int n)
{
  int t = threadIdx.x;
  int d = t & 63;
  int node = blockIdx.x*4 + (t >> 6);
  if (node >= n) return;
  int s = off[node], e = s + deg[node];
  const ushort* a8 = (const ushort*)agg8;   // [node][64] fp8-pairs
  float a0 = 0.f, a1 = 0.f;
  int p = s;
  for (; p+16 <= e; p += 16){
    ushort u[16];
    #pragma unroll
    for (int j=0;j<16;j++) u[j] = a8[(size_t)adj[p+j]*64 + d];
    #pragma unroll
    for (int j=0;j<16;j++){
      float2v f = dec8(u[j]);
      a0 += f[0]; a1 += f[1];
    }
  }
  for (; p+4 <= e; p += 4){
    ushort u0 = a8[(size_t)adj[p  ]*64 + d];
    ushort u1 = a8[(size_t)adj[p+1]*64 + d];
    ushort u2 = a8[(size_t)adj[p+2]*64 + d];
    ushort u3 = a8[(size_t)adj[p+3]*64 + d];
    float2v f0 = dec8(u0), f1 = dec8(u1), f2 = dec8(u2), f3 = dec8(u3);
    a0 += (f0[0]+f1[0]) + (f2[0]+f3[0]);
    a1 += (f0[1]+f1[1]) + (f2[1]+f3[1]);
  }
  for (; p < e; p++){
    float2v f = dec8(a8[(size_t)adj[p]*64 + d]);
    a0 += f[0]; a1 += f[1];
  }
  int cnt = e - s;
  float inv = 1.f / (float)((cnt > 1)? cnt : 1);
  unsigned rt = ((const unsigned*)rootsrc)[(size_t)node*64 + d];
  unsigned rs = ((const unsigned*)ressrc)[(size_t)node*64 + d];
  float o0 = fmaxf(a0*inv + bias[2*d]   + blo(rt), 0.f) + blo(rs);
  float o1 = fmaxf(a1*inv + bias[2*d+1] + bhi(rt), 0.f) + bhi(rs);
  ((unsigned*)out)[(size_t)node*64 + d] = (unsigned)f2b(o0) | ((unsigned)f2b(o1) << 16);
}

// ================= GEMM1: weights-resident; hl1 output fp8, hr1 bf16 =================
__global__ __launch_bounds__(256) void gemm1_wres(
    const ushort* __restrict__ h, int N,
    const ushort* __restrict__ Wl1f, const ushort* __restrict__ Wr1f,
    unsigned char* __restrict__ q8, ushort* __restrict__ hr1)
{
  __shared__ __align__(16) ushort Bs[32768];
  int t = threadIdx.x, w = t>>6, lane = t&63, lq = lane&15, quad = lane>>4;
  int tile = blockIdx.x;
  #pragma unroll
  for (int j=0;j<16;j++){
    int r = w + j*4;
    int m = r>>5, g = r&31;
    const ushort* Wm = m ? Wr1f : Wl1f;
    glds16(Wm + (size_t)g*512 + lane*8, Bs + r*512);
  }
  short8 av[2][4];
  int row0 = tile*128 + w*32;
  #pragma unroll
  for (int mt=0;mt<2;mt++){
    int row = row0 + mt*16 + lq; if (row >= N) row = N-1;
    #pragma unroll
    for (int ks=0;ks<4;ks++)
      av[mt][ks] = *(const short8*)(h + (size_t)row*128 + ks*32 + quad*8);
  }
  __syncthreads();
  #pragma unroll
  for (int m=0;m<2;m++){
    float4v acc[2][8];
    #pragma unroll
    for (int i=0;i<2;i++)
      #pragma unroll
      for (int j=0;j<8;j++)
        #pragma unroll
        for (int r=0;r<4;r++) acc[i][j][r] = 0.f;
    #pragma unroll
    for (int ks=0;ks<4;ks++){
      #pragma unroll
      for (int nt=0;nt<8;nt++){
        short8 bf = *(const short8*)(Bs + ((m*32 + ks*8 + nt)*64 + lane)*8);
        acc[0][nt] = __builtin_amdgcn_mfma_f32_16x16x32_bf16(av[0][ks], bf, acc[0][nt], 0,0,0);
        acc[1][nt] = __builtin_amdgcn_mfma_f32_16x16x32_bf16(av[1][ks], bf, acc[1][nt], 0,0,0);
      }
    }
    #pragma unroll
    for (int mt=0;mt<2;mt++){
      #pragma unroll
      for (int r=0;r<4;r++){
        int row = row0 + mt*16 + quad*4 + r;
        if (row < N){
          if (m == 0){
            #pragma unroll
            for (int nt=0;nt<8;nt++)
              q8[(size_t)row*128 + nt*16 + lq] = enc8(acc[mt][nt][r]);
          } else {
            #pragma unroll
            for (int nt=0;nt<8;nt++)
              hr1[(size_t)row*128 + nt*16 + lq] = f2b(acc[mt][nt][r]);
          }
        }
      }
    }
  }
}

// ================= combine1 + head fused (fp8 gather, 16-deep) =================
__global__ __launch_bounds__(256) void combine1_head(
    const unsigned char* __restrict__ agg8, const ushort* __restrict__ hr1,
    const ushort* __restrict__ h, const float* __restrict__ bl1,
    const int* __restrict__ off, const int* __restrict__ deg, const int* __restrict__ adj,
    const ushort* __restrict__ W1f, const float* __restrict__ b1,
    const float* __restrict__ W2, const float* __restrict__ b2,
    const float* __restrict__ alogit, const float* __restrict__ rer,
    float* __restrict__ out, int n)
{
  __shared__ __align__(16) ushort W1s[8192];
  __shared__ __align__(16) ushort h2s[16*136];
  int t = threadIdx.x, w = t>>6, lane = t&63, lq = lane&15, quad = lane>>4;
  #pragma unroll
  for (int j=0;j<4;j++){
    int g = w + j*4;
    glds16(W1f + (size_t)g*512 + lane*8, W1s + g*512);
  }
  int node0 = blockIdx.x*16;
  unsigned* h2u = (unsigned*)h2s;
  const ushort* a8 = (const ushort*)agg8;
  #pragma unroll
  for (int j=0;j<4;j++){
    int node = node0 + w*4 + j;
    float o0 = 0.f, o1 = 0.f;
    if (node < n){
      int s = off[node], e = s + deg[node];
      float a0 = 0.f, a1 = 0.f;
      int p = s;
      for (; p+16 <= e; p += 16){
        ushort u[16];
        #pragma unroll
        for (int jj=0;jj<16;jj++) u[jj] = a8[(size_t)adj[p+jj]*64 + lane];
        #pragma unroll
        for (int jj=0;jj<16;jj++){
          float2v f = dec8(u[jj]);
          a0 += f[0]; a1 += f[1];
        }
      }
      for (; p+4 <= e; p += 4){
        ushort u0 = a8[(size_t)adj[p  ]*64 + lane];
        ushort u1 = a8[(size_t)adj[p+1]*64 + lane];
        ushort u2 = a8[(size_t)adj[p+2]*64 + lane];
        ushort u3 = a8[(size_t)adj[p+3]*64 + lane];
        float2v f0 = dec8(u0), f1 = dec8(u1), f2 = dec8(u2), f3 = dec8(u3);
        a0 += (f0[0]+f1[0]) + (f2[0]+f3[0]);
        a1 += (f0[1]+f1[1]) + (f2[1]+f3[1]);
      }
      for (; p < e; p++){
        float2v f = dec8(a8[(size_t)adj[p]*64 + lane]);
        a0 += f[0]; a1 += f[1];
      }
      int cnt = e - s;
      float inv = 1.f / (float)((cnt > 1)? cnt : 1);
      unsigned rt = ((const unsigned*)hr1)[(size_t)node*64 + lane];
      unsigned rs = ((const unsigned*)h)[(size_t)node*64 + lane];
      o0 = fmaxf(a0*inv + bl1[2*lane]   + blo(rt), 0.f) + blo(rs);
      o1 = fmaxf(a1*inv + bl1[2*lane+1] + bhi(rt), 0.f) + bhi(rs);
    }
    h2u[(w*4+j)*68 + lane] = (unsigned)f2b(o0) | ((unsigned)f2b(o1) << 16);
  }
  __syncthreads();

  short8 av[4];
  #pragma unroll
  for (int ks=0;ks<4;ks++)
    av[ks] = *(const short8*)(h2s + lq*136 + ks*32 + quad*8);
  float4v acc[4];
  #pragma unroll
  for (int nt=0;nt<4;nt++)
    #pragma unroll
    for (int r=0;r<4;r++) acc[nt][r] = 0.f;
  #pragma unroll
  for (int ks=0;ks<4;ks++){
    #pragma unroll
    for (int nt=0;nt<4;nt++){
      short8 bf = *(const short8*)(W1s + ((ks*4 + nt)*64 + lane)*8);
      acc[nt] = __builtin_amdgcn_mfma_f32_16x16x32_bf16(av[ks], bf, acc[nt], 0,0,0);
    }
  }
  float al = alogit[0];
  float a  = 1.f / (1.f + __expf(-al));
  float pw[4] = {0.f,0.f,0.f,0.f};
  #pragma unroll
  for (int nt=0; nt<4; nt++){
    int c = nt*16 + lq;
    float w2 = W2[c];
    float bb = b1[c];
    #pragma unroll
    for (int r=0; r<4; r++)
      pw[r] += fmaxf(acc[nt][r] + bb, 0.f) * w2;
  }
  #pragma unroll
  for (int mask=1; mask<16; mask<<=1){
    #pragma unroll
    for (int r=0; r<4; r++)
      pw[r] += __shfl_xor(pw[r], mask);
  }
  if (lq == 0){
    #pragma unroll
    for (int r=0; r<4; r++){
      int rl = quad*4 + r;
      if ((rl >> 2) == w){
        int node = node0 + rl;
        if (node < n)
          out[node] = a * rer[node] + (1.f - a) * (pw[r] + b2[0]);
      }
    }
  }
}

extern "C" void kernel_launch(void* const* d_in, const int* in_sizes, int n_in,
                              void* d_out, int out_size, void* d_ws, size_t ws_size,
                              hipStream_t stream)
{
  (void)n_in; (void)out_size; (void)ws_size;
  const float* x    = (const float*)d_in[0];
  const int*   ei   = (const int*)d_in[1];
  const float* rer  = (const float*)d_in[2];
  const float* Wp   = (const float*)d_in[3];
  const float* bp   = (const float*)d_in[4];
  const float* Wl0  = (const float*)d_in[5];
  const float* bl0  = (const float*)d_in[6];
  const float* Wr0  = (const float*)d_in[7];
  const float* Wl1  = (const float*)d_in[8];
  const float* bl1  = (const float*)d_in[9];
  const float* Wr1  = (const float*)d_in[10];
  const float* W1   = (const float*)d_in[11];
  const float* b1   = (const float*)d_in[12];
  const float* W2   = (const float*)d_in[13];
  const float* b2   = (const float*)d_in[14];
  const float* alogit = (const float*)d_in[15];

  const int N = in_sizes[2];      // 50000
  const int E = in_sizes[1] / 2;  // 800000
  const int* src = ei;
  const int* dst = ei + E;
  const int NB = (N + NPB - 1) / NPB;        // 98
  const int nstripe = (N + 15) / 16;         // 3125
  const int ntile = (N + 127) / 128;         // 391
  const int nPart = (E + EPB - 1) / EPB;     // 391
  const int nConv = (nstripe*512 + 255)/256; // 6250

  // workspace layout
  ushort* U = (ushort*)d_ws;
  ushort* xb  = U;                           // stripe-frag x
  ushort* xp  = xb + (size_t)nstripe*512*8;  // [N][128] residual
  ushort* xr0 = xp  + (size_t)N*DH;          // root0; reused as hr1
  ushort* h   = xr0 + (size_t)N*DH;
  unsigned char* q8 = (unsigned char*)(h + (size_t)N*DH);  // [N][128] fp8 (xl0 then hl1)
  ushort* Wpf  = (ushort*)(q8 + (size_t)N*DH);
  ushort* Wl0f = Wpf  + (size_t)4096*8;
  ushort* Wr0f = Wl0f + (size_t)4096*8;
  ushort* Wl1f = Wr0f + (size_t)4096*8;
  ushort* Wr1f = Wl1f + (size_t)2048*8;
  ushort* W1f  = Wr1f + (size_t)2048*8;
  int* I = (int*)(W1f + (size_t)1024*8);
  int* bucketCnt = I;
  int* off   = bucketCnt + NBMAX;
  int* deg   = off + N;
  int* pairS = deg + N;
  int* pairD = pairS + (size_t)NB*SLOTS;
  int* adj   = pairD + (size_t)NB*SLOTS;

  hipMemsetAsync(bucketCnt, 0, NBMAX*sizeof(int), stream);

  // L1: [partition | convert | prep]
  fused_front<<<nPart + nConv + 68, 256, 0, stream>>>(
      x, N, xb, nstripe, Wp, Wl0, Wr0, Wl1, Wr1, W1,
      Wpf, Wl0f, Wr0f, Wl1f, Wr1f, W1f,
      src, dst, E, NB, bucketCnt, pairS, pairD, nPart, nConv);

  // L2: [GEMM0 | bucket_csr]  (xl0 -> q8 fp8)
  gemm0_csr<<<768 + NB, 256, 0, stream>>>(
      xb, N, nstripe, 768, Wpf, Wl0f, Wr0f, bp, xp, q8, xr0,
      bucketCnt, pairS, pairD, off, deg, adj);

  // combine0: h = relu(mean_fp8(q8[nbrs]) + bl0 + xr0) + xp
  combine0_f8<<<(N+3)/4, 256, 0, stream>>>(q8, xr0, xp, bl0, off, deg, adj, h, N);

  // GEMM1: hl1 -> q8 (fp8), hr1 -> xr0 (bf16)
  gemm1_wres<<<ntile, 256, 0, stream>>>(h, N, Wl1f, Wr1f, q8, xr0);

  // combine1+head fused
  combine1_head<<<(N+15)/16, 256, 0, stream>>>(
      q8, xr0, h, bl1, off, deg, adj, W1f, b1, W2, b2, alogit, rer, (float*)d_out, N);
}